// Round 1
// 550.455 us; speedup vs baseline: 1.0049x; 1.0049x over previous
//
#include <hip/hip_runtime.h>
#include <hip/hip_bf16.h>

typedef unsigned short u16;
typedef unsigned int u32;
typedef __bf16 bf16x8 __attribute__((ext_vector_type(8)));
typedef float f32x4 __attribute__((ext_vector_type(4)));
typedef u32 u32x4 __attribute__((ext_vector_type(4)));

#define QKV_LD 6144
#define KOFF 4096
#define VOFF 5120
#define HD 128
#define DIM 4096

__device__ __forceinline__ u16 f2bf(float f) {
  union { __hip_bfloat16 h; u16 u; } c;
  c.h = __float2bfloat16(f);
  return c.u;
}
__device__ __forceinline__ float bf2f(u16 u) {
  union { u16 u; __hip_bfloat16 h; } c;
  c.u = u;
  return __bfloat162float(c.h);
}

typedef __attribute__((address_space(1))) const u32 gas_u32;
typedef __attribute__((address_space(3))) u32 las_u32;
__device__ __forceinline__ void async16(const u16* g, u16* l) {
  __builtin_amdgcn_global_load_lds((gas_u32*)g, (las_u32*)l, 16, 0, 0);
}

__device__ __forceinline__ void store_out(u16* p, float v) { *p = f2bf(v); }
__device__ __forceinline__ void store_out(float* p, float v) { *p = v; }

// ---------------- f32 -> bf16 convert, 8 elems/thread ----------------
__global__ __launch_bounds__(256) void cvt_kernel(const float* __restrict__ src,
                                                  u16* __restrict__ dst, int n8) {
  int i = blockIdx.x * 256 + threadIdx.x;
  if (i >= n8) return;
  const f32x4* s4 = (const f32x4*)src;
  f32x4 a = s4[2 * i], b = s4[2 * i + 1];
  u32x4 o;
  o[0] = (u32)f2bf(a[0]) | ((u32)f2bf(a[1]) << 16);
  o[1] = (u32)f2bf(a[2]) | ((u32)f2bf(a[3]) << 16);
  o[2] = (u32)f2bf(b[0]) | ((u32)f2bf(b[1]) << 16);
  o[3] = (u32)f2bf(b[2]) | ((u32)f2bf(b[3]) << 16);
  ((u32x4*)dst)[i] = o;
}

// ---------------- NT GEMM (legacy 128x128, kept for WO) ----------------
template <typename OutT>
__global__ __launch_bounds__(256, 2) void gemm_nt(const u16* __restrict__ A,
                                                  const u16* __restrict__ B,
                                                  OutT* __restrict__ C, int N, int K) {
  __shared__ u16 As[128 * 32];
  __shared__ u16 Bs[128 * 32];
  const int tid = threadIdx.x;
  const int wave = tid >> 6;
  const int lane = tid & 63;
  const int quad = lane >> 4;
  const int l16 = lane & 15;
  const int bm = blockIdx.y;
  const int bn = blockIdx.x;
  const int wm = (wave >> 1) * 64;
  const int wn = (wave & 1) * 64;

  f32x4 acc[4][4];
#pragma unroll
  for (int i = 0; i < 4; ++i)
#pragma unroll
    for (int j = 0; j < 4; ++j) {
      f32x4 z = {0.f, 0.f, 0.f, 0.f};
      acc[i][j] = z;
    }

  const int srow0 = wave * 32 + (lane >> 2);
  const int scol = (((lane & 3) ^ ((lane >> 2) & 3)) * 8);
  u16* ldsA0 = &As[(wave * 2 + 0) * 512];
  u16* ldsA1 = &As[(wave * 2 + 1) * 512];
  u16* ldsB0 = &Bs[(wave * 2 + 0) * 512];
  u16* ldsB1 = &Bs[(wave * 2 + 1) * 512];
  const u16* Ag0 = A + (size_t)(bm * 128 + srow0) * K + scol;
  const u16* Ag1 = A + (size_t)(bm * 128 + srow0 + 16) * K + scol;
  const u16* Bg0 = B + (size_t)(bn * 128 + srow0) * K + scol;
  const u16* Bg1 = B + (size_t)(bn * 128 + srow0 + 16) * K + scol;

  int aoff[4], boff[4];
#pragma unroll
  for (int mi = 0; mi < 4; ++mi)
    aoff[mi] = (wm + mi * 16 + l16) * 32 + ((quad ^ (l16 & 3)) * 8);
#pragma unroll
  for (int ni = 0; ni < 4; ++ni)
    boff[ni] = (wn + ni * 16 + l16) * 32 + ((quad ^ (l16 & 3)) * 8);

  for (int k0 = 0; k0 < K; k0 += 32) {
    __syncthreads();
    async16(Ag0 + k0, ldsA0);
    async16(Ag1 + k0, ldsA1);
    async16(Bg0 + k0, ldsB0);
    async16(Bg1 + k0, ldsB1);
    __syncthreads();
    bf16x8 af[4], bb[4];
#pragma unroll
    for (int mi = 0; mi < 4; ++mi) af[mi] = *(const bf16x8*)&As[aoff[mi]];
#pragma unroll
    for (int ni = 0; ni < 4; ++ni) bb[ni] = *(const bf16x8*)&Bs[boff[ni]];
#pragma unroll
    for (int mi = 0; mi < 4; ++mi)
#pragma unroll
      for (int ni = 0; ni < 4; ++ni)
        acc[mi][ni] = __builtin_amdgcn_mfma_f32_16x16x32_bf16(af[mi], bb[ni], acc[mi][ni], 0, 0, 0);
  }

#pragma unroll
  for (int mi = 0; mi < 4; ++mi) {
    int row = bm * 128 + wm + mi * 16 + quad * 4;
#pragma unroll
    for (int ni = 0; ni < 4; ++ni) {
      int col = bn * 128 + wn + ni * 16 + l16;
#pragma unroll
      for (int r = 0; r < 4; ++r)
        store_out(&C[(size_t)(row + r) * N + col], acc[mi][ni][r]);
    }
  }
}

// ---------------- NT GEMM: 256x256 tile, 8-phase counted-vmcnt schedule -----
// T1 (XCD swizzle) + T2 (XOR-swizzled LDS via pre-swizzled global src) +
// T3/T4 (8 phases, vmcnt(6) only at phases 4 and 8) + T5 (setprio on MFMA).
// 8 waves (2M x 4N); quadrant order q00,q01,q11,q10 per K-tile (BK=64);
// slots [A0,A1,B0,B1] of 128 rows x 64 k each; one half-tile staged per
// phase, always >=1 barrier-pair after that slot's last LDS read:
//   ph1: buf1.A1<-t+1   ph2: buf0.A0<-t+2  ph3: buf0.B0<-t+2  ph4: buf0.B1<-t+2
//   ph5: buf0.A1<-t+2   ph6: buf1.A0<-t+3  ph7: buf1.B0<-t+3  ph8: buf1.B1<-t+3
// vmcnt(6) at ph4/ph8 leaves exactly the 3 newest half-tiles in flight.
#define BAR8 __builtin_amdgcn_s_barrier()
#define LGKM0                                                     \
  do {                                                            \
    asm volatile("s_waitcnt lgkmcnt(0)" ::: "memory");            \
    __builtin_amdgcn_sched_barrier(0);                            \
  } while (0)
#define VMC(n)                                                    \
  do {                                                            \
    asm volatile("s_waitcnt vmcnt(" #n ")" ::: "memory");         \
    __builtin_amdgcn_sched_barrier(0);                            \
  } while (0)

#define LDA8(buf, half, arr)                                                     \
  _Pragma("unroll") for (int mi = 0; mi < 4; ++mi) {                             \
    const int r_ = wm * 64 + mi * 16 + l16;                                      \
    const u16* p_ = &lds[buf][half][r_ * 64];                                    \
    _Pragma("unroll") for (int ks = 0; ks < 2; ++ks)                             \
      arr[mi][ks] = *(const bf16x8*)(p_ + (((ks * 4 + quad) ^ (r_ & 7)) << 3));  \
  }

#define LDB8(buf, half, arr)                                                     \
  _Pragma("unroll") for (int ni = 0; ni < 2; ++ni) {                             \
    const int r_ = wn * 32 + ni * 16 + l16;                                      \
    const u16* p_ = &lds[buf][2 + (half)][r_ * 64];                              \
    _Pragma("unroll") for (int ks = 0; ks < 2; ++ks)                             \
      arr[ni][ks] = *(const bf16x8*)(p_ + (((ks * 4 + quad) ^ (r_ & 7)) << 3));  \
  }

#define MMA8(qm, qn, af, bf)                                                       \
  __builtin_amdgcn_s_setprio(1);                                                   \
  _Pragma("unroll") for (int mi = 0; mi < 4; ++mi)                                 \
  _Pragma("unroll") for (int ni = 0; ni < 2; ++ni)                                 \
  _Pragma("unroll") for (int ks = 0; ks < 2; ++ks)                                 \
    acc[(qm) * 4 + mi][(qn) * 2 + ni] = __builtin_amdgcn_mfma_f32_16x16x32_bf16(   \
        af[mi][ks], bf[ni][ks], acc[(qm) * 4 + mi][(qn) * 2 + ni], 0, 0, 0);       \
  __builtin_amdgcn_s_setprio(0);

template <typename OutT>
__global__ __launch_bounds__(512, 2) void gemm_nt8(const u16* __restrict__ A,
                                                   const u16* __restrict__ B,
                                                   OutT* __restrict__ C,
                                                   int N, int K, int MT) {
  __shared__ u16 lds[2][4][128 * 64];  // [buf][A0,A1,B0,B1][row*64 + elem]
  const int tid = threadIdx.x;
  const int wave = tid >> 6;
  const int lane = tid & 63;
  const int quad = lane >> 4;
  const int l16 = lane & 15;
  const int wm = wave >> 2;  // 0..1 : 64-row band within a 128-row half
  const int wn = wave & 3;   // 0..3 : 32-col band within a 128-col half

  // bijective XCD-aware swizzle
  const int nwg = gridDim.x;
  const int bid = blockIdx.x;
  const int qq = nwg >> 3, rr8 = nwg & 7, xcd = bid & 7, off = bid >> 3;
  const int wg = (xcd < rr8 ? xcd * (qq + 1) : rr8 * (qq + 1) + (xcd - rr8) * qq) + off;
  const int bm = wg % MT;
  const int bn = wg / MT;

  const int NIT = K >> 7;  // two 64-wide K-tiles per iteration

  // staging geometry: thread t covers row (t>>3) of a 64-row j-block,
  // 16B granule (t&7), reading the XOR-swizzled global granule so the
  // linear global_load_lds dest yields swizzled LDS (T2, both-sides rule).
  const int srow = (wave << 3) + (lane >> 3);
  const int sgran = (lane & 7) ^ ((lane >> 3) & 7);
  const u16* Abase = A + (size_t)(bm * 256 + srow) * K + sgran * 8;
  const u16* Bbase = B + (size_t)(bn * 256 + srow) * K + sgran * 8;

  auto stage = [&](const u16* base, int h, int kt, u16* slot) {
    const u16* g = base + (size_t)(h * 128) * K + kt * 64;
    u16* s = slot + wave * (8 * 64);
    async16(g, s);
    async16(g + (size_t)64 * K, s + 64 * 64);
  };

  f32x4 acc[8][4];
#pragma unroll
  for (int i = 0; i < 8; ++i)
#pragma unroll
    for (int j = 0; j < 4; ++j) {
      f32x4 z = {0.f, 0.f, 0.f, 0.f};
      acc[i][j] = z;
    }

  // prologue: tile0 (all 4 halves) + tile1 (A0,B0,B1); A1 of tile1 comes at ph1
  stage(Abase, 0, 0, &lds[0][0][0]);
  stage(Bbase, 0, 0, &lds[0][2][0]);
  stage(Bbase, 1, 0, &lds[0][3][0]);
  stage(Abase, 1, 0, &lds[0][1][0]);
  stage(Abase, 0, 1, &lds[1][0][0]);
  stage(Bbase, 0, 1, &lds[1][2][0]);
  stage(Bbase, 1, 1, &lds[1][3][0]);
  VMC(6);  // drain tile0's 8 loads; tile1's 6 stay in flight
  BAR8;

  bf16x8 a0[4][2], a1[4][2], b0[2][2], b1[2][2];
  for (int it = 0; it < NIT; ++it) {
    const int t2 = 2 * it + 2, t3 = 2 * it + 3;
    const bool more = (it + 1 < NIT);

    // ---- ph1: q00 on buf0 ----
    LDA8(0, 0, a0);
    LDB8(0, 0, b0);
    stage(Abase, 1, 2 * it + 1, &lds[1][1][0]);  // buf1.A1 <- t+1 (read ph7)
    BAR8; LGKM0;
    MMA8(0, 0, a0, b0);
    BAR8;
    // ---- ph2: q01 (reuse a0) ----
    LDB8(0, 1, b1);
    if (more) stage(Abase, 0, t2, &lds[0][0][0]);
    BAR8; LGKM0;
    MMA8(0, 1, a0, b1);
    BAR8;
    // ---- ph3: q11 (reuse b1) ----
    LDA8(0, 1, a1);
    if (more) stage(Bbase, 0, t2, &lds[0][2][0]);
    BAR8; LGKM0;
    MMA8(1, 1, a1, b1);
    BAR8;
    // ---- ph4: q10 (reuse a1, b0); tile boundary vmcnt ----
    if (more) stage(Bbase, 1, t2, &lds[0][3][0]);
    BAR8; LGKM0;
    MMA8(1, 0, a1, b0);
    if (more) { VMC(6); } else { VMC(0); }
    BAR8;
    // ---- ph5: q00 on buf1 ----
    LDA8(1, 0, a0);
    LDB8(1, 0, b0);
    if (more) stage(Abase, 1, t2, &lds[0][1][0]);
    BAR8; LGKM0;
    MMA8(0, 0, a0, b0);
    BAR8;
    // ---- ph6: q01 ----
    LDB8(1, 1, b1);
    if (more) stage(Abase, 0, t3, &lds[1][0][0]);
    BAR8; LGKM0;
    MMA8(0, 1, a0, b1);
    BAR8;
    // ---- ph7: q11 ----
    LDA8(1, 1, a1);
    if (more) stage(Bbase, 0, t3, &lds[1][2][0]);
    BAR8; LGKM0;
    MMA8(1, 1, a1, b1);
    BAR8;
    // ---- ph8: q10; tile boundary vmcnt ----
    if (more) stage(Bbase, 1, t3, &lds[1][3][0]);
    BAR8; LGKM0;
    MMA8(1, 0, a1, b0);
    if (more) { VMC(6); } else { VMC(0); }
    BAR8;
  }

#pragma unroll
  for (int qm = 0; qm < 2; ++qm)
#pragma unroll
    for (int mi = 0; mi < 4; ++mi) {
      int row = bm * 256 + qm * 128 + wm * 64 + mi * 16 + quad * 4;
#pragma unroll
      for (int qn = 0; qn < 2; ++qn)
#pragma unroll
        for (int ni = 0; ni < 2; ++ni) {
          int col = bn * 256 + qn * 128 + wn * 32 + ni * 16 + l16;
#pragma unroll
          for (int r = 0; r < 4; ++r)
            store_out(&C[(size_t)(row + r) * N + col], acc[qm * 4 + mi][qn * 2 + ni][r]);
        }
    }
}

// ---------------- RoPE in-place on q,k regions of qkv (bf16) ----------------
__global__ __launch_bounds__(256) void rope_kernel(u16* qkv, const float* __restrict__ fcos,
                                                   const float* __restrict__ fsin) {
  int idx = blockIdx.x * 256 + threadIdx.x;
  int row, colbase, fi;
  if (idx < 2048 * 2048) {
    row = idx >> 11;
    int pi = idx & 2047;
    fi = pi & 63;
    colbase = (pi >> 6) * 128 + fi * 2;
  } else {
    int j = idx - 2048 * 2048;
    row = j >> 9;
    int pj = j & 511;
    fi = pj & 63;
    colbase = KOFF + (pj >> 6) * 128 + fi * 2;
  }
  float c = fcos[row * 64 + fi], s = fsin[row * 64 + fi];
  u32* p = (u32*)(qkv + (size_t)row * QKV_LD + colbase);
  u32 v = *p;
  float a = bf2f((u16)(v & 0xffffu));
  float b = bf2f((u16)(v >> 16));
  float xr = a * c - b * s;
  float xi = a * s + b * c;
  *p = (u32)f2bf(xr) | ((u32)f2bf(xi) << 16);
}

// ---------------- V transpose: qkv V region [s][kvh*128+d] -> vt[kvh][d][s] --
__global__ __launch_bounds__(256) void vtrans_kernel(const u16* __restrict__ qkv,
                                                     u16* __restrict__ vt) {
  __shared__ u16 Ls[64 * 72];
  const int tid = threadIdx.x;
  const int st = blockIdx.x, dt = blockIdx.y, kvh = blockIdx.z;
#pragma unroll
  for (int t = 0; t < 2; ++t) {
    int g = t * 256 + tid;
    int s = g >> 3, c = g & 7;
    u32x4 v = *(const u32x4*)(qkv + (size_t)(st * 64 + s) * QKV_LD + VOFF + kvh * HD + dt * 64 + c * 8);
    *(u32x4*)&Ls[s * 72 + c * 8] = v;
  }
  __syncthreads();
#pragma unroll
  for (int t = 0; t < 2; ++t) {
    int g = t * 256 + tid;
    int d = g >> 3, c2 = g & 7;
    u32x4 o;
#pragma unroll
    for (int j = 0; j < 4; ++j) {
      u16 lo = Ls[(c2 * 8 + 2 * j) * 72 + d];
      u16 hi = Ls[(c2 * 8 + 2 * j + 1) * 72 + d];
      o[j] = (u32)lo | ((u32)hi << 16);
    }
    *(u32x4*)(vt + (size_t)(kvh * HD + dt * 64 + d) * 2048 + st * 64 + c2 * 8) = o;
  }
}

// ---------------- Flash attention, causal, GQA 4:1 ----------------
__global__ __launch_bounds__(256, 2) void flash_kernel(const u16* __restrict__ qkv,
                                                       const u16* __restrict__ vt,
                                                       u16* __restrict__ attnb) {
  __shared__ u16 Kl[2][64 * 128];   // [key][d], 16B granules XOR-swizzled by key&15
  __shared__ u16 VtL[2][128 * 64];  // [d][key], 16B granules XOR-swizzled by d&7
  __shared__ u16 Pl[4][16 * 72];    // per-wave P round-trip (reused for both m-blocks)
  const int tid = threadIdx.x;
  const int wave = tid >> 6;
  const int lane = tid & 63;
  const int quad = lane >> 4;
  const int l16 = lane & 15;
  const int lid = blockIdx.x;
  const int h = lid & 31;
  const int z = lid >> 5;              // 0..15
  const int qt = (z < 8) ? z : 23 - z; // pairs (lid, lid+256) sum to 34 iters
  const int kvh = h >> 2;
  const float scale = 0.08838834764831845f; // 1/sqrt(128)
  const int nkt = 2 * qt + 2;

  const int krow_l = (lane >> 4);
  const int kcol_l = (lane & 15);
  const int vd_l = (lane >> 3);
  const int vc = (lane & 7) ^ ((lane >> 3) & 7);

  const u16* kbase = qkv + (size_t)KOFF + kvh * HD;
  const u16* vbase = vt + (size_t)kvh * HD * 2048;

  bf16x8 qf[2][4];
#pragma unroll
  for (int mi = 0; mi < 2; ++mi) {
    const u16* qp = qkv + (size_t)(qt * 128 + wave * 32 + mi * 16 + l16) * QKV_LD + h * HD + quad * 8;
#pragma unroll
    for (int ks = 0; ks < 4; ++ks) qf[mi][ks] = *(const bf16x8*)(qp + ks * 32);
  }

  f32x4 o[2][8];
#pragma unroll
  for (int mi = 0; mi < 2; ++mi)
#pragma unroll
    for (int i = 0; i < 8; ++i) { f32x4 zz = {0.f, 0.f, 0.f, 0.f}; o[mi][i] = zz; }
  float lacc[2] = {0.f, 0.f};

#pragma unroll
  for (int t = 0; t < 4; ++t) {
    int i = wave * 4 + t;
    int row = i * 4 + krow_l;
    int c = kcol_l ^ (row & 15);
    async16(kbase + (size_t)row * QKV_LD + c * 8, &Kl[0][i * 512]);
  }
#pragma unroll
  for (int t = 0; t < 4; ++t) {
    int i = wave * 4 + t;
    int d = i * 8 + vd_l;
    async16(vbase + (size_t)d * 2048 + vc * 8, &VtL[0][i * 512]);
  }

  for (int kt = 0; kt < nkt; ++kt) {
    const int cur = kt & 1;
    __syncthreads();

    f32x4 s4[2][4];
#pragma unroll
    for (int mi = 0; mi < 2; ++mi)
#pragma unroll
      for (int nb = 0; nb < 4; ++nb) { f32x4 zz = {0.f, 0.f, 0.f, 0.f}; s4[mi][nb] = zz; }
#pragma unroll
    for (int nb = 0; nb < 4; ++nb) {
#pragma unroll
      for (int ks = 0; ks < 4; ++ks) {
        int rr = nb * 16 + l16;
        int cc = ((ks * 4 + quad) ^ l16) * 8;
        bf16x8 kf = *(const bf16x8*)&Kl[cur][rr * 128 + cc];
        s4[0][nb] = __builtin_amdgcn_mfma_f32_16x16x32_bf16(qf[0][ks], kf, s4[0][nb], 0, 0, 0);
        s4[1][nb] = __builtin_amdgcn_mfma_f32_16x16x32_bf16(qf[1][ks], kf, s4[1][nb], 0, 0, 0);
      }
    }

    bf16x8 vb[16];
#pragma unroll
    for (int db = 0; db < 8; ++db) {
      int dd = db * 16 + l16;
#pragma unroll
      for (int ks2 = 0; ks2 < 2; ++ks2) {
        int c = (ks2 * 4 + quad) ^ (dd & 7);
        vb[db * 2 + ks2] = *(const bf16x8*)&VtL[cur][dd * 64 + c * 8];
      }
    }

    float p[2][4][4];
    const bool diag = (kt >= 2 * qt);
    if (diag) {
#pragma unroll
      for (int mi = 0; mi < 2; ++mi)
#pragma unroll
        for (int nb = 0; nb < 4; ++nb) {
          int col = kt * 64 + nb * 16 + l16;
#pragma unroll
          for (int r = 0; r < 4; ++r) {
            int row = qt * 128 + wave * 32 + mi * 16 + quad * 4 + r;
            p[mi][nb][r] = (col > row) ? 0.f : __expf(s4[mi][nb][r] * scale);
          }
        }
    } else {
#pragma unroll
      for (int mi = 0; mi < 2; ++mi)
#pragma unroll
        for (int nb = 0; nb < 4; ++nb)
#pragma unroll
          for (int r = 0; r < 4; ++r)
            p[mi][nb][r] = __expf(s4[mi][nb][r] * scale);
    }

    bf16x8 pa[2][2];
#pragma unroll
    for (int mi = 0; mi < 2; ++mi) {
#pragma unroll
      for (int nb = 0; nb < 4; ++nb)
#pragma unroll
        for (int r = 0; r < 4; ++r)
          Pl[wave][(quad * 4 + r) * 72 + nb * 16 + l16] = f2bf(p[mi][nb][r]);
      __asm__ __volatile__("s_waitcnt lgkmcnt(0)" ::: "memory");
#pragma unroll
      for (int ks2 = 0; ks2 < 2; ++ks2)
        pa[mi][ks2] = *(const bf16x8*)&Pl[wave][l16 * 72 + ks2 * 32 + quad * 8];
    }

#pragma unroll
    for (int mi = 0; mi < 2; ++mi) {
      float sm = 0.f;
#pragma unroll
      for (int ks2 = 0; ks2 < 2; ++ks2)
#pragma unroll
        for (int j = 0; j < 8; ++j) sm += (float)pa[mi][ks2][j];
      sm += __shfl_xor(sm, 16);
      sm += __shfl_xor(sm, 32);
      lacc[mi] += sm;
    }

    if (kt + 1 < nkt) {
      const u16* kb = kbase + (size_t)(kt + 1) * 64 * QKV_LD;
      const u16* vb2 = vbase + (kt + 1) * 64;
#pragma unroll
      for (int t = 0; t < 4; ++t) {
        int i = wave * 4 + t;
        int row = i * 4 + krow_l;
        int c = kcol_l ^ (row & 15);
        async16(kb + (size_t)row * QKV_LD + c * 8, &Kl[1 - cur][i * 512]);
      }
#pragma unroll
      for (int t = 0; t < 4; ++t) {
        int i = wave * 4 + t;
        int d = i * 8 + vd_l;
        async16(vb2 + (size_t)d * 2048 + vc * 8, &VtL[1 - cur][i * 512]);
      }
    }

#pragma unroll
    for (int mi = 0; mi < 2; ++mi)
#pragma unroll
      for (int db = 0; db < 8; ++db)
#pragma unroll
        for (int ks2 = 0; ks2 < 2; ++ks2)
          o[mi][db] = __builtin_amdgcn_mfma_f32_16x16x32_bf16(pa[mi][ks2], vb[db * 2 + ks2], o[mi][db], 0, 0, 0);
  }

  float* lsh = (float*)&Pl[wave][0];
  if (quad == 0) {
    lsh[l16] = lacc[0];
    lsh[16 + l16] = lacc[1];
  }
  __asm__ __volatile__("s_waitcnt lgkmcnt(0)" ::: "memory");
  __builtin_amdgcn_wave_barrier();
  f32x4 inv[2];
#pragma unroll
  for (int mi = 0; mi < 2; ++mi) {
    f32x4 lv = *(const f32x4*)&lsh[mi * 16 + quad * 4];
#pragma unroll
    for (int r = 0; r < 4; ++r) inv[mi][r] = 1.f / lv[r];
  }
#pragma unroll
  for (int mi = 0; mi < 2; ++mi)
#pragma unroll
    for (int db = 0; db < 8; ++db)
#pragma unroll
      for (int r = 0; r < 4; ++r) {
        int row = qt * 128 + wave * 32 + mi * 16 + quad * 4 + r;
        int col = h * HD + db * 16 + l16;
        attnb[(size_t)row * DIM + col] = f2bf(o[mi][db][r] * inv[mi][r]);
      }
}

extern "C" void kernel_launch(void* const* d_in, const int* in_sizes, int n_in,
                              void* d_out, int out_size, void* d_ws, size_t ws_size,
                              hipStream_t stream) {
  (void)in_sizes; (void)n_in; (void)out_size; (void)ws_size;
  const float* x    = (const float*)d_in[0];
  const float* wq   = (const float*)d_in[1];
  const float* wk   = (const float*)d_in[2];
  const float* wv   = (const float*)d_in[3];
  const float* wo   = (const float*)d_in[4];
  const float* fcos = (const float*)d_in[5];
  const float* fsin = (const float*)d_in[6];
  float* out = (float*)d_out;

  char* ws = (char*)d_ws;
  u16* xb    = (u16*)(ws);                        // 2048x4096 bf16   (16.78 MB)
  u16* wqkvb = (u16*)(ws + (size_t)16777216);     // 6144x4096 bf16   (50.33 MB)
  u16* wob   = (u16*)(ws + (size_t)67108864);     // 4096x4096 bf16   (33.55 MB)
  u16* qkv   = (u16*)(ws + (size_t)100663296);    // 2048x6144 bf16   (25.17 MB)
  u16* attnb = (u16*)(ws + (size_t)125829120);    // 2048x4096 bf16   (16.78 MB)
  u16* vtb   = (u16*)(ws);                        // 8x128x2048 bf16 (4.19 MB) overlays dead xb

  // f32 -> bf16 (fused [wq;wk;wv] so QKV is a single NT GEMM)
  cvt_kernel<<<4096, 256, 0, stream>>>(x, xb, 1048576);
  cvt_kernel<<<8192, 256, 0, stream>>>(wq, wqkvb, 2097152);
  cvt_kernel<<<2048, 256, 0, stream>>>(wk, wqkvb + 16777216, 524288);
  cvt_kernel<<<2048, 256, 0, stream>>>(wv, wqkvb + 20971520, 524288);
  cvt_kernel<<<8192, 256, 0, stream>>>(wo, wob, 2097152);

  // qkv[s, 0:4096]=Q, [4096:5120]=K, [5120:6144]=V
  // 256^2 8-phase GEMM: grid = (2048/256)*(6144/256) = 192 blocks, 1/CU
  gemm_nt8<u16><<<dim3(192), 512, 0, stream>>>(xb, wqkvb, qkv, 6144, 4096, 8);
  // V^T (xb is dead after the QKV GEMM; vtb overlays it)
  vtrans_kernel<<<dim3(32, 2, 8), 256, 0, stream>>>(qkv, vtb);
  rope_kernel<<<20480, 256, 0, stream>>>(qkv, fcos, fsin);
  flash_kernel<<<512, 256, 0, stream>>>(qkv, vtb, attnb);
  // WO GEMM stays on the 128^2 kernel: at 256^2 it would be only 128 blocks
  // (half the CUs idle) — port it once the 8-phase template is validated.
  gemm_nt<float><<<dim3(32, 16), 256, 0, stream>>>(attnb, wob, out, 4096, 4096);
}

// Round 2
// 535.216 us; speedup vs baseline: 1.0336x; 1.0285x over previous
//
#include <hip/hip_runtime.h>
#include <hip/hip_bf16.h>

typedef unsigned short u16;
typedef unsigned int u32;
typedef __bf16 bf16x8 __attribute__((ext_vector_type(8)));
typedef float f32x4 __attribute__((ext_vector_type(4)));
typedef u32 u32x4 __attribute__((ext_vector_type(4)));

#define QKV_LD 6144
#define KOFF 4096
#define VOFF 5120
#define HD 128
#define DIM 4096

__device__ __forceinline__ u16 f2bf(float f) {
  union { __hip_bfloat16 h; u16 u; } c;
  c.h = __float2bfloat16(f);
  return c.u;
}
__device__ __forceinline__ float bf2f(u16 u) {
  union { u16 u; __hip_bfloat16 h; } c;
  c.u = u;
  return __bfloat162float(c.h);
}

typedef __attribute__((address_space(1))) const u32 gas_u32;
typedef __attribute__((address_space(3))) u32 las_u32;
__device__ __forceinline__ void async16(const u16* g, u16* l) {
  __builtin_amdgcn_global_load_lds((gas_u32*)g, (las_u32*)l, 16, 0, 0);
}

__device__ __forceinline__ void store_out(u16* p, float v) { *p = f2bf(v); }
__device__ __forceinline__ void store_out(float* p, float v) { *p = v; }

// ---------------- f32 -> bf16 convert, 8 elems/thread ----------------
__global__ __launch_bounds__(256) void cvt_kernel(const float* __restrict__ src,
                                                  u16* __restrict__ dst, int n8) {
  int i = blockIdx.x * 256 + threadIdx.x;
  if (i >= n8) return;
  const f32x4* s4 = (const f32x4*)src;
  f32x4 a = s4[2 * i], b = s4[2 * i + 1];
  u32x4 o;
  o[0] = (u32)f2bf(a[0]) | ((u32)f2bf(a[1]) << 16);
  o[1] = (u32)f2bf(a[2]) | ((u32)f2bf(a[3]) << 16);
  o[2] = (u32)f2bf(b[0]) | ((u32)f2bf(b[1]) << 16);
  o[3] = (u32)f2bf(b[2]) | ((u32)f2bf(b[3]) << 16);
  ((u32x4*)dst)[i] = o;
}

// ======================= 8-phase GEMM machinery =======================
// T1 (XCD swizzle) + T2 (XOR-swizzled LDS via pre-swizzled global src) +
// T3/T4 (8 phases, counted vmcnt, never 0 in main loop) + T5 (setprio).
// NOTE (round-1 post-mortem): NO sched_barrier(0) after the waits — with
// plain-C++ ds_reads the compiler tracks deps and emits fine-grained
// lgkmcnt; pinning serialized DS vs MFMA pipes (m141 failure mode,
// measured here as MfmaUtil stuck at 34%).
#define BAR8 __builtin_amdgcn_s_barrier()
#define LGKM0 asm volatile("s_waitcnt lgkmcnt(0)" ::: "memory")
#define VMC(n) asm volatile("s_waitcnt vmcnt(" #n ")" ::: "memory")

// ---------------- NT GEMM: 256x256 tile, 8-phase ----------------
// 8 waves (2M x 4N); quadrant order q00,q01,q11,q10 per K-tile (BK=64);
// slots [A0,A1,B0,B1] of 128 rows x 64 k; one half-tile staged per phase,
// always >=1 barrier-pair after that slot's last LDS read:
//   ph1: buf1.A1<-t+1   ph2: buf0.A0<-t+2  ph3: buf0.B0<-t+2  ph4: buf0.B1<-t+2
//   ph5: buf0.A1<-t+2   ph6: buf1.A0<-t+3  ph7: buf1.B0<-t+3  ph8: buf1.B1<-t+3
// vmcnt(6) at ph4/ph8 leaves exactly the 3 newest half-tiles in flight.
#define LDA8(buf, half, arr)                                                     \
  _Pragma("unroll") for (int mi = 0; mi < 4; ++mi) {                             \
    const int r_ = wm * 64 + mi * 16 + l16;                                      \
    const u16* p_ = &lds[buf][half][r_ * 64];                                    \
    _Pragma("unroll") for (int ks = 0; ks < 2; ++ks)                             \
      arr[mi][ks] = *(const bf16x8*)(p_ + (((ks * 4 + quad) ^ (r_ & 7)) << 3));  \
  }

#define LDB8(buf, half, arr)                                                     \
  _Pragma("unroll") for (int ni = 0; ni < 2; ++ni) {                             \
    const int r_ = wn * 32 + ni * 16 + l16;                                      \
    const u16* p_ = &lds[buf][2 + (half)][r_ * 64];                              \
    _Pragma("unroll") for (int ks = 0; ks < 2; ++ks)                             \
      arr[ni][ks] = *(const bf16x8*)(p_ + (((ks * 4 + quad) ^ (r_ & 7)) << 3));  \
  }

#define MMA8(qm, qn, af, bf)                                                       \
  __builtin_amdgcn_s_setprio(1);                                                   \
  _Pragma("unroll") for (int mi = 0; mi < 4; ++mi)                                 \
  _Pragma("unroll") for (int ni = 0; ni < 2; ++ni)                                 \
  _Pragma("unroll") for (int ks = 0; ks < 2; ++ks)                                 \
    acc[(qm) * 4 + mi][(qn) * 2 + ni] = __builtin_amdgcn_mfma_f32_16x16x32_bf16(   \
        af[mi][ks], bf[ni][ks], acc[(qm) * 4 + mi][(qn) * 2 + ni], 0, 0, 0);       \
  __builtin_amdgcn_s_setprio(0);

template <typename OutT>
__global__ __launch_bounds__(512, 2) void gemm_nt8(const u16* __restrict__ A,
                                                   const u16* __restrict__ B,
                                                   OutT* __restrict__ C,
                                                   int N, int K, int MT) {
  __shared__ u16 lds[2][4][128 * 64];  // [buf][A0,A1,B0,B1][row*64 + elem]
  const int tid = threadIdx.x;
  const int wave = tid >> 6;
  const int lane = tid & 63;
  const int quad = lane >> 4;
  const int l16 = lane & 15;
  const int wm = wave >> 2;  // 0..1 : 64-row band within a 128-row half
  const int wn = wave & 3;   // 0..3 : 32-col band within a 128-col half

  // bijective XCD-aware swizzle
  const int nwg = gridDim.x;
  const int bid = blockIdx.x;
  const int qq = nwg >> 3, rr8 = nwg & 7, xcd = bid & 7, off = bid >> 3;
  const int wg = (xcd < rr8 ? xcd * (qq + 1) : rr8 * (qq + 1) + (xcd - rr8) * qq) + off;
  const int bm = wg % MT;
  const int bn = wg / MT;

  const int NIT = K >> 7;  // two 64-wide K-tiles per iteration

  // staging geometry: thread t covers row (t>>3) of a 64-row j-block,
  // 16B granule (t&7), reading the XOR-swizzled global granule so the
  // linear global_load_lds dest yields swizzled LDS (T2, both-sides rule).
  const int srow = (wave << 3) + (lane >> 3);
  const int sgran = (lane & 7) ^ ((lane >> 3) & 7);
  const u16* Abase = A + (size_t)(bm * 256 + srow) * K + sgran * 8;
  const u16* Bbase = B + (size_t)(bn * 256 + srow) * K + sgran * 8;

  auto stage = [&](const u16* base, int h, int kt, u16* slot) {
    const u16* g = base + (size_t)(h * 128) * K + kt * 64;
    u16* s = slot + wave * (8 * 64);
    async16(g, s);
    async16(g + (size_t)64 * K, s + 64 * 64);
  };

  f32x4 acc[8][4];
#pragma unroll
  for (int i = 0; i < 8; ++i)
#pragma unroll
    for (int j = 0; j < 4; ++j) {
      f32x4 z = {0.f, 0.f, 0.f, 0.f};
      acc[i][j] = z;
    }

  // prologue: tile0 (all 4 halves) + tile1 (A0,B0,B1); A1 of tile1 comes at ph1
  stage(Abase, 0, 0, &lds[0][0][0]);
  stage(Bbase, 0, 0, &lds[0][2][0]);
  stage(Bbase, 1, 0, &lds[0][3][0]);
  stage(Abase, 1, 0, &lds[0][1][0]);
  stage(Abase, 0, 1, &lds[1][0][0]);
  stage(Bbase, 0, 1, &lds[1][2][0]);
  stage(Bbase, 1, 1, &lds[1][3][0]);
  VMC(6);  // drain tile0's 8 loads; tile1's 6 stay in flight
  BAR8;

  bf16x8 a0[4][2], a1[4][2], b0[2][2], b1[2][2];
  for (int it = 0; it < NIT; ++it) {
    const int t2 = 2 * it + 2, t3 = 2 * it + 3;
    const bool more = (it + 1 < NIT);

    // ---- ph1: q00 on buf0 ----
    LDA8(0, 0, a0);
    LDB8(0, 0, b0);
    stage(Abase, 1, 2 * it + 1, &lds[1][1][0]);  // buf1.A1 <- t+1 (read ph7)
    BAR8; LGKM0;
    MMA8(0, 0, a0, b0);
    BAR8;
    // ---- ph2: q01 (reuse a0) ----
    LDB8(0, 1, b1);
    if (more) stage(Abase, 0, t2, &lds[0][0][0]);
    BAR8; LGKM0;
    MMA8(0, 1, a0, b1);
    BAR8;
    // ---- ph3: q11 (reuse b1) ----
    LDA8(0, 1, a1);
    if (more) stage(Bbase, 0, t2, &lds[0][2][0]);
    BAR8; LGKM0;
    MMA8(1, 1, a1, b1);
    BAR8;
    // ---- ph4: q10 (reuse a1, b0); tile boundary vmcnt ----
    if (more) stage(Bbase, 1, t2, &lds[0][3][0]);
    BAR8; LGKM0;
    MMA8(1, 0, a1, b0);
    if (more) { VMC(6); } else { VMC(0); }
    BAR8;
    // ---- ph5: q00 on buf1 ----
    LDA8(1, 0, a0);
    LDB8(1, 0, b0);
    if (more) stage(Abase, 1, t2, &lds[0][1][0]);
    BAR8; LGKM0;
    MMA8(0, 0, a0, b0);
    BAR8;
    // ---- ph6: q01 ----
    LDB8(1, 1, b1);
    if (more) stage(Abase, 0, t3, &lds[1][0][0]);
    BAR8; LGKM0;
    MMA8(0, 1, a0, b1);
    BAR8;
    // ---- ph7: q11 ----
    LDA8(1, 1, a1);
    if (more) stage(Bbase, 0, t3, &lds[1][2][0]);
    BAR8; LGKM0;
    MMA8(1, 1, a1, b1);
    BAR8;
    // ---- ph8: q10; tile boundary vmcnt ----
    if (more) stage(Bbase, 1, t3, &lds[1][3][0]);
    BAR8; LGKM0;
    MMA8(1, 0, a1, b0);
    if (more) { VMC(6); } else { VMC(0); }
    BAR8;
  }

#pragma unroll
  for (int qm = 0; qm < 2; ++qm)
#pragma unroll
    for (int mi = 0; mi < 4; ++mi) {
      int row = bm * 256 + qm * 128 + wm * 64 + mi * 16 + quad * 4;
#pragma unroll
      for (int qn = 0; qn < 2; ++qn)
#pragma unroll
        for (int ni = 0; ni < 2; ++ni) {
          int col = bn * 256 + qn * 128 + wn * 32 + ni * 16 + l16;
#pragma unroll
          for (int r = 0; r < 4; ++r)
            store_out(&C[(size_t)(row + r) * N + col], acc[qm * 4 + mi][qn * 2 + ni][r]);
        }
    }
}

// ---------------- NT GEMM: 128x256 tile, 8-phase (exact 256-block fill) -----
// Same skeleton; 3 LDS slots per buf {A(128rows), B0(cols 0-127), B1(128-255)}.
// All A-fragments (both qm halves) read in ph1/ph5; 6 stages/iter:
//   ph2: buf0.B0<-t+2  ph3: buf0.A<-t+2  ph4: buf0.B1<-t+2
//   ph6: buf1.B0<-t+3  ph7: buf1.A<-t+3  ph8: buf1.B1<-t+3
// Slot lifetimes: A read ph1 -> staged ph3; B0 read ph1 -> ph2 (one
// barrier-pair later, same discipline as 256^2); B1 read ph2 -> ph4.
// vmcnt(6) at ph4/ph8 = exactly the 3 newest stages in flight.
#define LDAW(buf, arr)                                                               \
  _Pragma("unroll") for (int qm_ = 0; qm_ < 2; ++qm_)                                \
  _Pragma("unroll") for (int mi = 0; mi < 2; ++mi) {                                 \
    const int r_ = qm_ * 64 + wm * 32 + mi * 16 + l16;                               \
    const u16* p_ = &lds[buf][0][r_ * 64];                                           \
    _Pragma("unroll") for (int ks = 0; ks < 2; ++ks)                                 \
      arr[qm_][mi][ks] = *(const bf16x8*)(p_ + (((ks * 4 + quad) ^ (r_ & 7)) << 3)); \
  }

#define LDBW(buf, h, arr)                                                        \
  _Pragma("unroll") for (int ni = 0; ni < 2; ++ni) {                             \
    const int r_ = wn * 32 + ni * 16 + l16;                                      \
    const u16* p_ = &lds[buf][1 + (h)][r_ * 64];                                 \
    _Pragma("unroll") for (int ks = 0; ks < 2; ++ks)                             \
      arr[ni][ks] = *(const bf16x8*)(p_ + (((ks * 4 + quad) ^ (r_ & 7)) << 3));  \
  }

#define MMAW(qm, qn, af, bf)                                                       \
  __builtin_amdgcn_s_setprio(1);                                                   \
  _Pragma("unroll") for (int mi = 0; mi < 2; ++mi)                                 \
  _Pragma("unroll") for (int ni = 0; ni < 2; ++ni)                                 \
  _Pragma("unroll") for (int ks = 0; ks < 2; ++ks)                                 \
    acc[(qm) * 2 + mi][(qn) * 2 + ni] = __builtin_amdgcn_mfma_f32_16x16x32_bf16(   \
        af[qm][mi][ks], bf[ni][ks], acc[(qm) * 2 + mi][(qn) * 2 + ni], 0, 0, 0);   \
  __builtin_amdgcn_s_setprio(0);

template <typename OutT>
__global__ __launch_bounds__(512, 2) void gemm_nt8w(const u16* __restrict__ A,
                                                    const u16* __restrict__ B,
                                                    OutT* __restrict__ C,
                                                    int N, int K, int MT) {
  __shared__ u16 lds[2][3][128 * 64];  // [buf][A,B0,B1][row*64 + elem] (96 KiB)
  const int tid = threadIdx.x;
  const int wave = tid >> 6;
  const int lane = tid & 63;
  const int quad = lane >> 4;
  const int l16 = lane & 15;
  const int wm = wave >> 2;  // 0..1 : 32-row band within a 64-row half
  const int wn = wave & 3;   // 0..3 : 32-col band within a 128-col half

  const int nwg = gridDim.x;
  const int bid = blockIdx.x;
  const int qq = nwg >> 3, rr8 = nwg & 7, xcd = bid & 7, off = bid >> 3;
  const int wg = (xcd < rr8 ? xcd * (qq + 1) : rr8 * (qq + 1) + (xcd - rr8) * qq) + off;
  const int bm = wg % MT;
  const int bn = wg / MT;

  const int NIT = K >> 7;

  const int srow = (wave << 3) + (lane >> 3);
  const int sgran = (lane & 7) ^ ((lane >> 3) & 7);
  const u16* Abase = A + (size_t)(bm * 128 + srow) * K + sgran * 8;
  const u16* Bbase = B + (size_t)(bn * 256 + srow) * K + sgran * 8;

  auto stageA = [&](int buf, int kt) {
    const u16* g = Abase + (size_t)kt * 64;
    u16* s = &lds[buf][0][0] + wave * (8 * 64);
    async16(g, s);
    async16(g + (size_t)64 * K, s + 64 * 64);
  };
  auto stageB = [&](int buf, int h, int kt) {
    const u16* g = Bbase + (size_t)(h * 128) * K + kt * 64;
    u16* s = &lds[buf][1 + h][0] + wave * (8 * 64);
    async16(g, s);
    async16(g + (size_t)64 * K, s + 64 * 64);
  };

  f32x4 acc[4][4];
#pragma unroll
  for (int i = 0; i < 4; ++i)
#pragma unroll
    for (int j = 0; j < 4; ++j) {
      f32x4 z = {0.f, 0.f, 0.f, 0.f};
      acc[i][j] = z;
    }

  // prologue: tile0 + tile1 fully staged; vmcnt(6) drains tile0 only
  stageA(0, 0); stageB(0, 0, 0); stageB(0, 1, 0);
  stageA(1, 1); stageB(1, 0, 1); stageB(1, 1, 1);
  VMC(6);
  BAR8;

  bf16x8 a[2][2][2], b0f[2][2], b1f[2][2];
  for (int it = 0; it < NIT; ++it) {
    const int t2 = 2 * it + 2, t3 = 2 * it + 3;
    const bool more = (it + 1 < NIT);

    // ---- ph1: q00 on buf0 (all A-frags + B0) ----
    LDAW(0, a);
    LDBW(0, 0, b0f);
    BAR8; LGKM0;
    MMAW(0, 0, a, b0f);
    BAR8;
    // ---- ph2: q01 ----
    LDBW(0, 1, b1f);
    if (more) stageB(0, 0, t2);
    BAR8; LGKM0;
    MMAW(0, 1, a, b1f);
    BAR8;
    // ---- ph3: q11 ----
    if (more) stageA(0, t2);
    BAR8; LGKM0;
    MMAW(1, 1, a, b1f);
    BAR8;
    // ---- ph4: q10; tile boundary vmcnt ----
    if (more) stageB(0, 1, t2);
    BAR8; LGKM0;
    MMAW(1, 0, a, b0f);
    if (more) { VMC(6); } else { VMC(0); }
    BAR8;
    // ---- ph5: q00 on buf1 ----
    LDAW(1, a);
    LDBW(1, 0, b0f);
    BAR8; LGKM0;
    MMAW(0, 0, a, b0f);
    BAR8;
    // ---- ph6: q01 ----
    LDBW(1, 1, b1f);
    if (more) stageB(1, 0, t3);
    BAR8; LGKM0;
    MMAW(0, 1, a, b1f);
    BAR8;
    // ---- ph7: q11 ----
    if (more) stageA(1, t3);
    BAR8; LGKM0;
    MMAW(1, 1, a, b1f);
    BAR8;
    // ---- ph8: q10; tile boundary vmcnt ----
    if (more) stageB(1, 1, t3);
    BAR8; LGKM0;
    MMAW(1, 0, a, b0f);
    if (more) { VMC(6); } else { VMC(0); }
    BAR8;
  }

#pragma unroll
  for (int qm = 0; qm < 2; ++qm)
#pragma unroll
    for (int mi = 0; mi < 2; ++mi) {
      int row = bm * 128 + qm * 64 + wm * 32 + mi * 16 + quad * 4;
#pragma unroll
      for (int qn = 0; qn < 2; ++qn)
#pragma unroll
        for (int ni = 0; ni < 2; ++ni) {
          int col = bn * 256 + qn * 128 + wn * 32 + ni * 16 + l16;
#pragma unroll
          for (int r = 0; r < 4; ++r)
            store_out(&C[(size_t)(row + r) * N + col], acc[qm * 2 + mi][qn * 2 + ni][r]);
        }
    }
}

// ---------------- RoPE in-place on q,k regions of qkv (bf16) ----------------
__global__ __launch_bounds__(256) void rope_kernel(u16* qkv, const float* __restrict__ fcos,
                                                   const float* __restrict__ fsin) {
  int idx = blockIdx.x * 256 + threadIdx.x;
  int row, colbase, fi;
  if (idx < 2048 * 2048) {
    row = idx >> 11;
    int pi = idx & 2047;
    fi = pi & 63;
    colbase = (pi >> 6) * 128 + fi * 2;
  } else {
    int j = idx - 2048 * 2048;
    row = j >> 9;
    int pj = j & 511;
    fi = pj & 63;
    colbase = KOFF + (pj >> 6) * 128 + fi * 2;
  }
  float c = fcos[row * 64 + fi], s = fsin[row * 64 + fi];
  u32* p = (u32*)(qkv + (size_t)row * QKV_LD + colbase);
  u32 v = *p;
  float a = bf2f((u16)(v & 0xffffu));
  float b = bf2f((u16)(v >> 16));
  float xr = a * c - b * s;
  float xi = a * s + b * c;
  *p = (u32)f2bf(xr) | ((u32)f2bf(xi) << 16);
}

// ---------------- V transpose: qkv V region [s][kvh*128+d] -> vt[kvh][d][s] --
__global__ __launch_bounds__(256) void vtrans_kernel(const u16* __restrict__ qkv,
                                                     u16* __restrict__ vt) {
  __shared__ u16 Ls[64 * 72];
  const int tid = threadIdx.x;
  const int st = blockIdx.x, dt = blockIdx.y, kvh = blockIdx.z;
#pragma unroll
  for (int t = 0; t < 2; ++t) {
    int g = t * 256 + tid;
    int s = g >> 3, c = g & 7;
    u32x4 v = *(const u32x4*)(qkv + (size_t)(st * 64 + s) * QKV_LD + VOFF + kvh * HD + dt * 64 + c * 8);
    *(u32x4*)&Ls[s * 72 + c * 8] = v;
  }
  __syncthreads();
#pragma unroll
  for (int t = 0; t < 2; ++t) {
    int g = t * 256 + tid;
    int d = g >> 3, c2 = g & 7;
    u32x4 o;
#pragma unroll
    for (int j = 0; j < 4; ++j) {
      u16 lo = Ls[(c2 * 8 + 2 * j) * 72 + d];
      u16 hi = Ls[(c2 * 8 + 2 * j + 1) * 72 + d];
      o[j] = (u32)lo | ((u32)hi << 16);
    }
    *(u32x4*)(vt + (size_t)(kvh * HD + dt * 64 + d) * 2048 + st * 64 + c2 * 8) = o;
  }
}

// ---------------- Flash attention, causal, GQA 4:1 ----------------
__global__ __launch_bounds__(256, 2) void flash_kernel(const u16* __restrict__ qkv,
                                                       const u16* __restrict__ vt,
                                                       u16* __restrict__ attnb) {
  __shared__ u16 Kl[2][64 * 128];   // [key][d], 16B granules XOR-swizzled by key&15
  __shared__ u16 VtL[2][128 * 64];  // [d][key], 16B granules XOR-swizzled by d&7
  __shared__ u16 Pl[4][16 * 72];    // per-wave P round-trip (reused for both m-blocks)
  const int tid = threadIdx.x;
  const int wave = tid >> 6;
  const int lane = tid & 63;
  const int quad = lane >> 4;
  const int l16 = lane & 15;
  const int lid = blockIdx.x;
  const int h = lid & 31;
  const int z = lid >> 5;              // 0..15
  const int qt = (z < 8) ? z : 23 - z; // pairs (lid, lid+256) sum to 34 iters
  const int kvh = h >> 2;
  const float scale = 0.08838834764831845f; // 1/sqrt(128)
  const int nkt = 2 * qt + 2;

  const int krow_l = (lane >> 4);
  const int kcol_l = (lane & 15);
  const int vd_l = (lane >> 3);
  const int vc = (lane & 7) ^ ((lane >> 3) & 7);

  const u16* kbase = qkv + (size_t)KOFF + kvh * HD;
  const u16* vbase = vt + (size_t)kvh * HD * 2048;

  bf16x8 qf[2][4];
#pragma unroll
  for (int mi = 0; mi < 2; ++mi) {
    const u16* qp = qkv + (size_t)(qt * 128 + wave * 32 + mi * 16 + l16) * QKV_LD + h * HD + quad * 8;
#pragma unroll
    for (int ks = 0; ks < 4; ++ks) qf[mi][ks] = *(const bf16x8*)(qp + ks * 32);
  }

  f32x4 o[2][8];
#pragma unroll
  for (int mi = 0; mi < 2; ++mi)
#pragma unroll
    for (int i = 0; i < 8; ++i) { f32x4 zz = {0.f, 0.f, 0.f, 0.f}; o[mi][i] = zz; }
  float lacc[2] = {0.f, 0.f};

#pragma unroll
  for (int t = 0; t < 4; ++t) {
    int i = wave * 4 + t;
    int row = i * 4 + krow_l;
    int c = kcol_l ^ (row & 15);
    async16(kbase + (size_t)row * QKV_LD + c * 8, &Kl[0][i * 512]);
  }
#pragma unroll
  for (int t = 0; t < 4; ++t) {
    int i = wave * 4 + t;
    int d = i * 8 + vd_l;
    async16(vbase + (size_t)d * 2048 + vc * 8, &VtL[0][i * 512]);
  }

  for (int kt = 0; kt < nkt; ++kt) {
    const int cur = kt & 1;
    __syncthreads();

    f32x4 s4[2][4];
#pragma unroll
    for (int mi = 0; mi < 2; ++mi)
#pragma unroll
      for (int nb = 0; nb < 4; ++nb) { f32x4 zz = {0.f, 0.f, 0.f, 0.f}; s4[mi][nb] = zz; }
#pragma unroll
    for (int nb = 0; nb < 4; ++nb) {
#pragma unroll
      for (int ks = 0; ks < 4; ++ks) {
        int rr = nb * 16 + l16;
        int cc = ((ks * 4 + quad) ^ l16) * 8;
        bf16x8 kf = *(const bf16x8*)&Kl[cur][rr * 128 + cc];
        s4[0][nb] = __builtin_amdgcn_mfma_f32_16x16x32_bf16(qf[0][ks], kf, s4[0][nb], 0, 0, 0);
        s4[1][nb] = __builtin_amdgcn_mfma_f32_16x16x32_bf16(qf[1][ks], kf, s4[1][nb], 0, 0, 0);
      }
    }

    bf16x8 vb[16];
#pragma unroll
    for (int db = 0; db < 8; ++db) {
      int dd = db * 16 + l16;
#pragma unroll
      for (int ks2 = 0; ks2 < 2; ++ks2) {
        int c = (ks2 * 4 + quad) ^ (dd & 7);
        vb[db * 2 + ks2] = *(const bf16x8*)&VtL[cur][dd * 64 + c * 8];
      }
    }

    float p[2][4][4];
    const bool diag = (kt >= 2 * qt);
    if (diag) {
#pragma unroll
      for (int mi = 0; mi < 2; ++mi)
#pragma unroll
        for (int nb = 0; nb < 4; ++nb) {
          int col = kt * 64 + nb * 16 + l16;
#pragma unroll
          for (int r = 0; r < 4; ++r) {
            int row = qt * 128 + wave * 32 + mi * 16 + quad * 4 + r;
            p[mi][nb][r] = (col > row) ? 0.f : __expf(s4[mi][nb][r] * scale);
          }
        }
    } else {
#pragma unroll
      for (int mi = 0; mi < 2; ++mi)
#pragma unroll
        for (int nb = 0; nb < 4; ++nb)
#pragma unroll
          for (int r = 0; r < 4; ++r)
            p[mi][nb][r] = __expf(s4[mi][nb][r] * scale);
    }

    bf16x8 pa[2][2];
#pragma unroll
    for (int mi = 0; mi < 2; ++mi) {
#pragma unroll
      for (int nb = 0; nb < 4; ++nb)
#pragma unroll
        for (int r = 0; r < 4; ++r)
          Pl[wave][(quad * 4 + r) * 72 + nb * 16 + l16] = f2bf(p[mi][nb][r]);
      __asm__ __volatile__("s_waitcnt lgkmcnt(0)" ::: "memory");
#pragma unroll
      for (int ks2 = 0; ks2 < 2; ++ks2)
        pa[mi][ks2] = *(const bf16x8*)&Pl[wave][l16 * 72 + ks2 * 32 + quad * 8];
    }

#pragma unroll
    for (int mi = 0; mi < 2; ++mi) {
      float sm = 0.f;
#pragma unroll
      for (int ks2 = 0; ks2 < 2; ++ks2)
#pragma unroll
        for (int j = 0; j < 8; ++j) sm += (float)pa[mi][ks2][j];
      sm += __shfl_xor(sm, 16);
      sm += __shfl_xor(sm, 32);
      lacc[mi] += sm;
    }

    if (kt + 1 < nkt) {
      const u16* kb = kbase + (size_t)(kt + 1) * 64 * QKV_LD;
      const u16* vb2 = vbase + (kt + 1) * 64;
#pragma unroll
      for (int t = 0; t < 4; ++t) {
        int i = wave * 4 + t;
        int row = i * 4 + krow_l;
        int c = kcol_l ^ (row & 15);
        async16(kb + (size_t)row * QKV_LD + c * 8, &Kl[1 - cur][i * 512]);
      }
#pragma unroll
      for (int t = 0; t < 4; ++t) {
        int i = wave * 4 + t;
        int d = i * 8 + vd_l;
        async16(vb2 + (size_t)d * 2048 + vc * 8, &VtL[1 - cur][i * 512]);
      }
    }

#pragma unroll
    for (int mi = 0; mi < 2; ++mi)
#pragma unroll
      for (int db = 0; db < 8; ++db)
#pragma unroll
        for (int ks2 = 0; ks2 < 2; ++ks2)
          o[mi][db] = __builtin_amdgcn_mfma_f32_16x16x32_bf16(pa[mi][ks2], vb[db * 2 + ks2], o[mi][db], 0, 0, 0);
  }

  float* lsh = (float*)&Pl[wave][0];
  if (quad == 0) {
    lsh[l16] = lacc[0];
    lsh[16 + l16] = lacc[1];
  }
  __asm__ __volatile__("s_waitcnt lgkmcnt(0)" ::: "memory");
  __builtin_amdgcn_wave_barrier();
  f32x4 inv[2];
#pragma unroll
  for (int mi = 0; mi < 2; ++mi) {
    f32x4 lv = *(const f32x4*)&lsh[mi * 16 + quad * 4];
#pragma unroll
    for (int r = 0; r < 4; ++r) inv[mi][r] = 1.f / lv[r];
  }
#pragma unroll
  for (int mi = 0; mi < 2; ++mi)
#pragma unroll
    for (int db = 0; db < 8; ++db)
#pragma unroll
      for (int r = 0; r < 4; ++r) {
        int row = qt * 128 + wave * 32 + mi * 16 + quad * 4 + r;
        int col = h * HD + db * 16 + l16;
        attnb[(size_t)row * DIM + col] = f2bf(o[mi][db][r] * inv[mi][r]);
      }
}

extern "C" void kernel_launch(void* const* d_in, const int* in_sizes, int n_in,
                              void* d_out, int out_size, void* d_ws, size_t ws_size,
                              hipStream_t stream) {
  (void)in_sizes; (void)n_in; (void)out_size; (void)ws_size;
  const float* x    = (const float*)d_in[0];
  const float* wq   = (const float*)d_in[1];
  const float* wk   = (const float*)d_in[2];
  const float* wv   = (const float*)d_in[3];
  const float* wo   = (const float*)d_in[4];
  const float* fcos = (const float*)d_in[5];
  const float* fsin = (const float*)d_in[6];
  float* out = (float*)d_out;

  char* ws = (char*)d_ws;
  u16* xb    = (u16*)(ws);                        // 2048x4096 bf16   (16.78 MB)
  u16* wqkvb = (u16*)(ws + (size_t)16777216);     // 6144x4096 bf16   (50.33 MB)
  u16* wob   = (u16*)(ws + (size_t)67108864);     // 4096x4096 bf16   (33.55 MB)
  u16* qkv   = (u16*)(ws + (size_t)100663296);    // 2048x6144 bf16   (25.17 MB)
  u16* attnb = (u16*)(ws + (size_t)125829120);    // 2048x4096 bf16   (16.78 MB)
  u16* vtb   = (u16*)(ws);                        // 8x128x2048 bf16 (4.19 MB) overlays dead xb

  // f32 -> bf16 (fused [wq;wk;wv] so QKV is a single NT GEMM)
  cvt_kernel<<<4096, 256, 0, stream>>>(x, xb, 1048576);
  cvt_kernel<<<8192, 256, 0, stream>>>(wq, wqkvb, 2097152);
  cvt_kernel<<<2048, 256, 0, stream>>>(wk, wqkvb + 16777216, 524288);
  cvt_kernel<<<2048, 256, 0, stream>>>(wv, wqkvb + 20971520, 524288);
  cvt_kernel<<<8192, 256, 0, stream>>>(wo, wob, 2097152);

  // qkv[s, 0:4096]=Q, [4096:5120]=K, [5120:6144]=V
  // 256^2 8-phase GEMM: grid = (2048/256)*(6144/256) = 192 blocks
  gemm_nt8<u16><<<dim3(192), 512, 0, stream>>>(xb, wqkvb, qkv, 6144, 4096, 8);
  // V^T (xb is dead after the QKV GEMM; vtb overlays it)
  vtrans_kernel<<<dim3(32, 2, 8), 256, 0, stream>>>(qkv, vtb);
  rope_kernel<<<20480, 256, 0, stream>>>(qkv, fcos, fsin);
  flash_kernel<<<512, 256, 0, stream>>>(qkv, vtb, attnb);
  // WO: 128x256-tile 8-phase, grid = (2048/128)*(4096/256) = 256 blocks (full fill)
  gemm_nt8w<float><<<dim3(256), 512, 0, stream>>>(attnb, wob, out, 4096, 4096, 16);
}

// Round 3
// 531.521 us; speedup vs baseline: 1.0407x; 1.0070x over previous
//
#include <hip/hip_runtime.h>
#include <hip/hip_bf16.h>

typedef unsigned short u16;
typedef unsigned int u32;
typedef __bf16 bf16x8 __attribute__((ext_vector_type(8)));
typedef float f32x4 __attribute__((ext_vector_type(4)));
typedef u32 u32x4 __attribute__((ext_vector_type(4)));

#define QKV_LD 6144
#define KOFF 4096
#define VOFF 5120
#define HD 128
#define DIM 4096

__device__ __forceinline__ u16 f2bf(float f) {
  union { __hip_bfloat16 h; u16 u; } c;
  c.h = __float2bfloat16(f);
  return c.u;
}
__device__ __forceinline__ float bf2f(u16 u) {
  union { u16 u; __hip_bfloat16 h; } c;
  c.u = u;
  return __bfloat162float(c.h);
}

typedef __attribute__((address_space(1))) const u32 gas_u32;
typedef __attribute__((address_space(3))) u32 las_u32;
__device__ __forceinline__ void async16(const u16* g, u16* l) {
  __builtin_amdgcn_global_load_lds((gas_u32*)g, (las_u32*)l, 16, 0, 0);
}

__device__ __forceinline__ void store_out(u16* p, float v) { *p = f2bf(v); }
__device__ __forceinline__ void store_out(float* p, float v) { *p = v; }

// ---------------- f32 -> bf16 convert, 8 elems/thread ----------------
__global__ __launch_bounds__(256) void cvt_kernel(const float* __restrict__ src,
                                                  u16* __restrict__ dst, int n8) {
  int i = blockIdx.x * 256 + threadIdx.x;
  if (i >= n8) return;
  const f32x4* s4 = (const f32x4*)src;
  f32x4 a = s4[2 * i], b = s4[2 * i + 1];
  u32x4 o;
  o[0] = (u32)f2bf(a[0]) | ((u32)f2bf(a[1]) << 16);
  o[1] = (u32)f2bf(a[2]) | ((u32)f2bf(a[3]) << 16);
  o[2] = (u32)f2bf(b[0]) | ((u32)f2bf(b[1]) << 16);
  o[3] = (u32)f2bf(b[2]) | ((u32)f2bf(b[3]) << 16);
  ((u32x4*)dst)[i] = o;
}

// ======================= 8-phase GEMM machinery =======================
// T1 (XCD swizzle) + T2 (XOR-swizzled LDS via pre-swizzled global src) +
// T3/T4 (8 phases, counted vmcnt, never 0 in main loop) + T5 (setprio).
// Round-2 post-mortem: the per-phase asm "s_waitcnt lgkmcnt(0)" with a
// "memory" clobber serialized the DS pipe against the MFMA pipe (measured
// 9330 cyc/iter vs m201's 6593 with identical instruction content). The
// ds_reads are plain C++ loads -> the compiler emits its own fine-grained
// lgkmcnt before each fragment's first MFMA use; no explicit drain needed.
// Only the counted VMC at tile boundaries (staging hazard) keeps "memory".
#define BAR8 __builtin_amdgcn_s_barrier()
#define VMC(n) asm volatile("s_waitcnt vmcnt(" #n ")" ::: "memory")

// ---------------- NT GEMM: 256x256 tile, 8-phase ----------------
// 8 waves (2M x 4N); quadrant order q00,q01,q11,q10 per K-tile (BK=64);
// slots [A0,A1,B0,B1] of 128 rows x 64 k; one half-tile staged per phase,
// always >=1 barrier-pair after that slot's last LDS read:
//   ph1: buf1.A1<-t+1   ph2: buf0.A0<-t+2  ph3: buf0.B0<-t+2  ph4: buf0.B1<-t+2
//   ph5: buf0.A1<-t+2   ph6: buf1.A0<-t+3  ph7: buf1.B0<-t+3  ph8: buf1.B1<-t+3
// vmcnt(6) at ph4/ph8 leaves exactly the 3 newest half-tiles in flight.
#define LDA8(buf, half, arr)                                                     \
  _Pragma("unroll") for (int mi = 0; mi < 4; ++mi) {                             \
    const int r_ = wm * 64 + mi * 16 + l16;                                      \
    const u16* p_ = &lds[buf][half][r_ * 64];                                    \
    _Pragma("unroll") for (int ks = 0; ks < 2; ++ks)                             \
      arr[mi][ks] = *(const bf16x8*)(p_ + (((ks * 4 + quad) ^ (r_ & 7)) << 3));  \
  }

#define LDB8(buf, half, arr)                                                     \
  _Pragma("unroll") for (int ni = 0; ni < 2; ++ni) {                             \
    const int r_ = wn * 32 + ni * 16 + l16;                                      \
    const u16* p_ = &lds[buf][2 + (half)][r_ * 64];                              \
    _Pragma("unroll") for (int ks = 0; ks < 2; ++ks)                             \
      arr[ni][ks] = *(const bf16x8*)(p_ + (((ks * 4 + quad) ^ (r_ & 7)) << 3));  \
  }

#define MMA8(qm, qn, af, bf)                                                       \
  __builtin_amdgcn_s_setprio(1);                                                   \
  _Pragma("unroll") for (int mi = 0; mi < 4; ++mi)                                 \
  _Pragma("unroll") for (int ni = 0; ni < 2; ++ni)                                 \
  _Pragma("unroll") for (int ks = 0; ks < 2; ++ks)                                 \
    acc[(qm) * 4 + mi][(qn) * 2 + ni] = __builtin_amdgcn_mfma_f32_16x16x32_bf16(   \
        af[mi][ks], bf[ni][ks], acc[(qm) * 4 + mi][(qn) * 2 + ni], 0, 0, 0);       \
  __builtin_amdgcn_s_setprio(0);

template <typename OutT>
__global__ __launch_bounds__(512, 2) void gemm_nt8(const u16* __restrict__ A,
                                                   const u16* __restrict__ B,
                                                   OutT* __restrict__ C,
                                                   int N, int K, int MT) {
  __shared__ u16 lds[2][4][128 * 64];  // [buf][A0,A1,B0,B1][row*64 + elem]
  const int tid = threadIdx.x;
  const int wave = tid >> 6;
  const int lane = tid & 63;
  const int quad = lane >> 4;
  const int l16 = lane & 15;
  const int wm = wave >> 2;  // 0..1 : 64-row band within a 128-row half
  const int wn = wave & 3;   // 0..3 : 32-col band within a 128-col half

  // bijective XCD-aware swizzle
  const int nwg = gridDim.x;
  const int bid = blockIdx.x;
  const int qq = nwg >> 3, rr8 = nwg & 7, xcd = bid & 7, off = bid >> 3;
  const int wg = (xcd < rr8 ? xcd * (qq + 1) : rr8 * (qq + 1) + (xcd - rr8) * qq) + off;
  const int bm = wg % MT;
  const int bn = wg / MT;

  const int NIT = K >> 7;  // two 64-wide K-tiles per iteration

  // staging geometry: thread t covers row (t>>3) of a 64-row j-block,
  // 16B granule (t&7), reading the XOR-swizzled global granule so the
  // linear global_load_lds dest yields swizzled LDS (T2, both-sides rule).
  const int srow = (wave << 3) + (lane >> 3);
  const int sgran = (lane & 7) ^ ((lane >> 3) & 7);
  const u16* Abase = A + (size_t)(bm * 256 + srow) * K + sgran * 8;
  const u16* Bbase = B + (size_t)(bn * 256 + srow) * K + sgran * 8;

  auto stage = [&](const u16* base, int h, int kt, u16* slot) {
    const u16* g = base + (size_t)(h * 128) * K + kt * 64;
    u16* s = slot + wave * (8 * 64);
    async16(g, s);
    async16(g + (size_t)64 * K, s + 64 * 64);
  };

  f32x4 acc[8][4];
#pragma unroll
  for (int i = 0; i < 8; ++i)
#pragma unroll
    for (int j = 0; j < 4; ++j) {
      f32x4 z = {0.f, 0.f, 0.f, 0.f};
      acc[i][j] = z;
    }

  // prologue: tile0 (all 4 halves) + tile1 (A0,B0,B1); A1 of tile1 comes at ph1
  stage(Abase, 0, 0, &lds[0][0][0]);
  stage(Bbase, 0, 0, &lds[0][2][0]);
  stage(Bbase, 1, 0, &lds[0][3][0]);
  stage(Abase, 1, 0, &lds[0][1][0]);
  stage(Abase, 0, 1, &lds[1][0][0]);
  stage(Bbase, 0, 1, &lds[1][2][0]);
  stage(Bbase, 1, 1, &lds[1][3][0]);
  VMC(6);  // drain tile0's 8 loads; tile1's 6 stay in flight
  BAR8;

  bf16x8 a0[4][2], a1[4][2], b0[2][2], b1[2][2];
  for (int it = 0; it < NIT; ++it) {
    const int t2 = 2 * it + 2, t3 = 2 * it + 3;
    const bool more = (it + 1 < NIT);

    // ---- ph1: q00 on buf0 ----
    LDA8(0, 0, a0);
    LDB8(0, 0, b0);
    stage(Abase, 1, 2 * it + 1, &lds[1][1][0]);  // buf1.A1 <- t+1 (read ph7)
    BAR8;
    MMA8(0, 0, a0, b0);
    BAR8;
    // ---- ph2: q01 (reuse a0) ----
    LDB8(0, 1, b1);
    if (more) stage(Abase, 0, t2, &lds[0][0][0]);
    BAR8;
    MMA8(0, 1, a0, b1);
    BAR8;
    // ---- ph3: q11 (reuse b1) ----
    LDA8(0, 1, a1);
    if (more) stage(Bbase, 0, t2, &lds[0][2][0]);
    BAR8;
    MMA8(1, 1, a1, b1);
    BAR8;
    // ---- ph4: q10 (reuse a1, b0); tile boundary vmcnt ----
    if (more) stage(Bbase, 1, t2, &lds[0][3][0]);
    BAR8;
    MMA8(1, 0, a1, b0);
    if (more) { VMC(6); } else { VMC(0); }
    BAR8;
    // ---- ph5: q00 on buf1 ----
    LDA8(1, 0, a0);
    LDB8(1, 0, b0);
    if (more) stage(Abase, 1, t2, &lds[0][1][0]);
    BAR8;
    MMA8(0, 0, a0, b0);
    BAR8;
    // ---- ph6: q01 ----
    LDB8(1, 1, b1);
    if (more) stage(Abase, 0, t3, &lds[1][0][0]);
    BAR8;
    MMA8(0, 1, a0, b1);
    BAR8;
    // ---- ph7: q11 ----
    LDA8(1, 1, a1);
    if (more) stage(Bbase, 0, t3, &lds[1][2][0]);
    BAR8;
    MMA8(1, 1, a1, b1);
    BAR8;
    // ---- ph8: q10; tile boundary vmcnt ----
    if (more) stage(Bbase, 1, t3, &lds[1][3][0]);
    BAR8;
    MMA8(1, 0, a1, b0);
    if (more) { VMC(6); } else { VMC(0); }
    BAR8;
  }

#pragma unroll
  for (int qm = 0; qm < 2; ++qm)
#pragma unroll
    for (int mi = 0; mi < 4; ++mi) {
      int row = bm * 256 + qm * 128 + wm * 64 + mi * 16 + quad * 4;
#pragma unroll
      for (int qn = 0; qn < 2; ++qn)
#pragma unroll
        for (int ni = 0; ni < 2; ++ni) {
          int col = bn * 256 + qn * 128 + wn * 32 + ni * 16 + l16;
#pragma unroll
          for (int r = 0; r < 4; ++r)
            store_out(&C[(size_t)(row + r) * N + col], acc[qm * 4 + mi][qn * 2 + ni][r]);
        }
    }
}

// ---------------- NT GEMM: 128x256 tile, 8-phase (exact 256-block fill) -----
// Same skeleton; 3 LDS slots per buf {A(128rows), B0(cols 0-127), B1(128-255)}.
#define LDAW(buf, arr)                                                               \
  _Pragma("unroll") for (int qm_ = 0; qm_ < 2; ++qm_)                                \
  _Pragma("unroll") for (int mi = 0; mi < 2; ++mi) {                                 \
    const int r_ = qm_ * 64 + wm * 32 + mi * 16 + l16;                               \
    const u16* p_ = &lds[buf][0][r_ * 64];                                           \
    _Pragma("unroll") for (int ks = 0; ks < 2; ++ks)                                 \
      arr[qm_][mi][ks] = *(const bf16x8*)(p_ + (((ks * 4 + quad) ^ (r_ & 7)) << 3)); \
  }

#define LDBW(buf, h, arr)                                                        \
  _Pragma("unroll") for (int ni = 0; ni < 2; ++ni) {                             \
    const int r_ = wn * 32 + ni * 16 + l16;                                      \
    const u16* p_ = &lds[buf][1 + (h)][r_ * 64];                                 \
    _Pragma("unroll") for (int ks = 0; ks < 2; ++ks)                             \
      arr[ni][ks] = *(const bf16x8*)(p_ + (((ks * 4 + quad) ^ (r_ & 7)) << 3));  \
  }

#define MMAW(qm, qn, af, bf)                                                       \
  __builtin_amdgcn_s_setprio(1);                                                   \
  _Pragma("unroll") for (int mi = 0; mi < 2; ++mi)                                 \
  _Pragma("unroll") for (int ni = 0; ni < 2; ++ni)                                 \
  _Pragma("unroll") for (int ks = 0; ks < 2; ++ks)                                 \
    acc[(qm) * 2 + mi][(qn) * 2 + ni] = __builtin_amdgcn_mfma_f32_16x16x32_bf16(   \
        af[qm][mi][ks], bf[ni][ks], acc[(qm) * 2 + mi][(qn) * 2 + ni], 0, 0, 0);   \
  __builtin_amdgcn_s_setprio(0);

template <typename OutT>
__global__ __launch_bounds__(512, 2) void gemm_nt8w(const u16* __restrict__ A,
                                                    const u16* __restrict__ B,
                                                    OutT* __restrict__ C,
                                                    int N, int K, int MT) {
  __shared__ u16 lds[2][3][128 * 64];  // [buf][A,B0,B1][row*64 + elem] (96 KiB)
  const int tid = threadIdx.x;
  const int wave = tid >> 6;
  const int lane = tid & 63;
  const int quad = lane >> 4;
  const int l16 = lane & 15;
  const int wm = wave >> 2;  // 0..1 : 32-row band within a 64-row half
  const int wn = wave & 3;   // 0..3 : 32-col band within a 128-col half

  const int nwg = gridDim.x;
  const int bid = blockIdx.x;
  const int qq = nwg >> 3, rr8 = nwg & 7, xcd = bid & 7, off = bid >> 3;
  const int wg = (xcd < rr8 ? xcd * (qq + 1) : rr8 * (qq + 1) + (xcd - rr8) * qq) + off;
  const int bm = wg % MT;
  const int bn = wg / MT;

  const int NIT = K >> 7;

  const int srow = (wave << 3) + (lane >> 3);
  const int sgran = (lane & 7) ^ ((lane >> 3) & 7);
  const u16* Abase = A + (size_t)(bm * 128 + srow) * K + sgran * 8;
  const u16* Bbase = B + (size_t)(bn * 256 + srow) * K + sgran * 8;

  auto stageA = [&](int buf, int kt) {
    const u16* g = Abase + (size_t)kt * 64;
    u16* s = &lds[buf][0][0] + wave * (8 * 64);
    async16(g, s);
    async16(g + (size_t)64 * K, s + 64 * 64);
  };
  auto stageB = [&](int buf, int h, int kt) {
    const u16* g = Bbase + (size_t)(h * 128) * K + kt * 64;
    u16* s = &lds[buf][1 + h][0] + wave * (8 * 64);
    async16(g, s);
    async16(g + (size_t)64 * K, s + 64 * 64);
  };

  f32x4 acc[4][4];
#pragma unroll
  for (int i = 0; i < 4; ++i)
#pragma unroll
    for (int j = 0; j < 4; ++j) {
      f32x4 z = {0.f, 0.f, 0.f, 0.f};
      acc[i][j] = z;
    }

  // prologue: tile0 + tile1 fully staged; vmcnt(6) drains tile0 only
  stageA(0, 0); stageB(0, 0, 0); stageB(0, 1, 0);
  stageA(1, 1); stageB(1, 0, 1); stageB(1, 1, 1);
  VMC(6);
  BAR8;

  bf16x8 a[2][2][2], b0f[2][2], b1f[2][2];
  for (int it = 0; it < NIT; ++it) {
    const int t2 = 2 * it + 2, t3 = 2 * it + 3;
    const bool more = (it + 1 < NIT);

    // ---- ph1: q00 on buf0 (all A-frags + B0) ----
    LDAW(0, a);
    LDBW(0, 0, b0f);
    BAR8;
    MMAW(0, 0, a, b0f);
    BAR8;
    // ---- ph2: q01 ----
    LDBW(0, 1, b1f);
    if (more) stageB(0, 0, t2);
    BAR8;
    MMAW(0, 1, a, b1f);
    BAR8;
    // ---- ph3: q11 ----
    if (more) stageA(0, t2);
    BAR8;
    MMAW(1, 1, a, b1f);
    BAR8;
    // ---- ph4: q10; tile boundary vmcnt ----
    if (more) stageB(0, 1, t2);
    BAR8;
    MMAW(1, 0, a, b0f);
    if (more) { VMC(6); } else { VMC(0); }
    BAR8;
    // ---- ph5: q00 on buf1 ----
    LDAW(1, a);
    LDBW(1, 0, b0f);
    BAR8;
    MMAW(0, 0, a, b0f);
    BAR8;
    // ---- ph6: q01 ----
    LDBW(1, 1, b1f);
    if (more) stageB(1, 0, t3);
    BAR8;
    MMAW(0, 1, a, b1f);
    BAR8;
    // ---- ph7: q11 ----
    if (more) stageA(1, t3);
    BAR8;
    MMAW(1, 1, a, b1f);
    BAR8;
    // ---- ph8: q10; tile boundary vmcnt ----
    if (more) stageB(1, 1, t3);
    BAR8;
    MMAW(1, 0, a, b0f);
    if (more) { VMC(6); } else { VMC(0); }
    BAR8;
  }

#pragma unroll
  for (int qm = 0; qm < 2; ++qm)
#pragma unroll
    for (int mi = 0; mi < 2; ++mi) {
      int row = bm * 128 + qm * 64 + wm * 32 + mi * 16 + quad * 4;
#pragma unroll
      for (int qn = 0; qn < 2; ++qn)
#pragma unroll
        for (int ni = 0; ni < 2; ++ni) {
          int col = bn * 256 + qn * 128 + wn * 32 + ni * 16 + l16;
#pragma unroll
          for (int r = 0; r < 4; ++r)
            store_out(&C[(size_t)(row + r) * N + col], acc[qm * 2 + mi][qn * 2 + ni][r]);
        }
    }
}

// ---------------- RoPE in-place on q,k regions of qkv (bf16) ----------------
__global__ __launch_bounds__(256) void rope_kernel(u16* qkv, const float* __restrict__ fcos,
                                                   const float* __restrict__ fsin) {
  int idx = blockIdx.x * 256 + threadIdx.x;
  int row, colbase, fi;
  if (idx < 2048 * 2048) {
    row = idx >> 11;
    int pi = idx & 2047;
    fi = pi & 63;
    colbase = (pi >> 6) * 128 + fi * 2;
  } else {
    int j = idx - 2048 * 2048;
    row = j >> 9;
    int pj = j & 511;
    fi = pj & 63;
    colbase = KOFF + (pj >> 6) * 128 + fi * 2;
  }
  float c = fcos[row * 64 + fi], s = fsin[row * 64 + fi];
  u32* p = (u32*)(qkv + (size_t)row * QKV_LD + colbase);
  u32 v = *p;
  float a = bf2f((u16)(v & 0xffffu));
  float b = bf2f((u16)(v >> 16));
  float xr = a * c - b * s;
  float xi = a * s + b * c;
  *p = (u32)f2bf(xr) | ((u32)f2bf(xi) << 16);
}

// ---------------- V transpose: qkv V region [s][kvh*128+d] -> vt[kvh][d][s] --
__global__ __launch_bounds__(256) void vtrans_kernel(const u16* __restrict__ qkv,
                                                     u16* __restrict__ vt) {
  __shared__ u16 Ls[64 * 72];
  const int tid = threadIdx.x;
  const int st = blockIdx.x, dt = blockIdx.y, kvh = blockIdx.z;
#pragma unroll
  for (int t = 0; t < 2; ++t) {
    int g = t * 256 + tid;
    int s = g >> 3, c = g & 7;
    u32x4 v = *(const u32x4*)(qkv + (size_t)(st * 64 + s) * QKV_LD + VOFF + kvh * HD + dt * 64 + c * 8);
    *(u32x4*)&Ls[s * 72 + c * 8] = v;
  }
  __syncthreads();
#pragma unroll
  for (int t = 0; t < 2; ++t) {
    int g = t * 256 + tid;
    int d = g >> 3, c2 = g & 7;
    u32x4 o;
#pragma unroll
    for (int j = 0; j < 4; ++j) {
      u16 lo = Ls[(c2 * 8 + 2 * j) * 72 + d];
      u16 hi = Ls[(c2 * 8 + 2 * j + 1) * 72 + d];
      o[j] = (u32)lo | ((u32)hi << 16);
    }
    *(u32x4*)(vt + (size_t)(kvh * HD + dt * 64 + d) * 2048 + st * 64 + c2 * 8) = o;
  }
}

// ---------------- Flash attention, causal, GQA 4:1 ----------------
__global__ __launch_bounds__(256, 2) void flash_kernel(const u16* __restrict__ qkv,
                                                       const u16* __restrict__ vt,
                                                       u16* __restrict__ attnb) {
  __shared__ u16 Kl[2][64 * 128];   // [key][d], 16B granules XOR-swizzled by key&15
  __shared__ u16 VtL[2][128 * 64];  // [d][key], 16B granules XOR-swizzled by d&7
  __shared__ u16 Pl[4][16 * 72];    // per-wave P round-trip (reused for both m-blocks)
  const int tid = threadIdx.x;
  const int wave = tid >> 6;
  const int lane = tid & 63;
  const int quad = lane >> 4;
  const int l16 = lane & 15;
  const int lid = blockIdx.x;
  const int h = lid & 31;
  const int z = lid >> 5;              // 0..15
  const int qt = (z < 8) ? z : 23 - z; // pairs (lid, lid+256) sum to 34 iters
  const int kvh = h >> 2;
  const float scale = 0.08838834764831845f; // 1/sqrt(128)
  const int nkt = 2 * qt + 2;

  const int krow_l = (lane >> 4);
  const int kcol_l = (lane & 15);
  const int vd_l = (lane >> 3);
  const int vc = (lane & 7) ^ ((lane >> 3) & 7);

  const u16* kbase = qkv + (size_t)KOFF + kvh * HD;
  const u16* vbase = vt + (size_t)kvh * HD * 2048;

  bf16x8 qf[2][4];
#pragma unroll
  for (int mi = 0; mi < 2; ++mi) {
    const u16* qp = qkv + (size_t)(qt * 128 + wave * 32 + mi * 16 + l16) * QKV_LD + h * HD + quad * 8;
#pragma unroll
    for (int ks = 0; ks < 4; ++ks) qf[mi][ks] = *(const bf16x8*)(qp + ks * 32);
  }

  f32x4 o[2][8];
#pragma unroll
  for (int mi = 0; mi < 2; ++mi)
#pragma unroll
    for (int i = 0; i < 8; ++i) { f32x4 zz = {0.f, 0.f, 0.f, 0.f}; o[mi][i] = zz; }
  float lacc[2] = {0.f, 0.f};

#pragma unroll
  for (int t = 0; t < 4; ++t) {
    int i = wave * 4 + t;
    int row = i * 4 + krow_l;
    int c = kcol_l ^ (row & 15);
    async16(kbase + (size_t)row * QKV_LD + c * 8, &Kl[0][i * 512]);
  }
#pragma unroll
  for (int t = 0; t < 4; ++t) {
    int i = wave * 4 + t;
    int d = i * 8 + vd_l;
    async16(vbase + (size_t)d * 2048 + vc * 8, &VtL[0][i * 512]);
  }

  for (int kt = 0; kt < nkt; ++kt) {
    const int cur = kt & 1;
    __syncthreads();

    f32x4 s4[2][4];
#pragma unroll
    for (int mi = 0; mi < 2; ++mi)
#pragma unroll
      for (int nb = 0; nb < 4; ++nb) { f32x4 zz = {0.f, 0.f, 0.f, 0.f}; s4[mi][nb] = zz; }
#pragma unroll
    for (int nb = 0; nb < 4; ++nb) {
#pragma unroll
      for (int ks = 0; ks < 4; ++ks) {
        int rr = nb * 16 + l16;
        int cc = ((ks * 4 + quad) ^ l16) * 8;
        bf16x8 kf = *(const bf16x8*)&Kl[cur][rr * 128 + cc];
        s4[0][nb] = __builtin_amdgcn_mfma_f32_16x16x32_bf16(qf[0][ks], kf, s4[0][nb], 0, 0, 0);
        s4[1][nb] = __builtin_amdgcn_mfma_f32_16x16x32_bf16(qf[1][ks], kf, s4[1][nb], 0, 0, 0);
      }
    }

    bf16x8 vb[16];
#pragma unroll
    for (int db = 0; db < 8; ++db) {
      int dd = db * 16 + l16;
#pragma unroll
      for (int ks2 = 0; ks2 < 2; ++ks2) {
        int c = (ks2 * 4 + quad) ^ (dd & 7);
        vb[db * 2 + ks2] = *(const bf16x8*)&VtL[cur][dd * 64 + c * 8];
      }
    }

    float p[2][4][4];
    const bool diag = (kt >= 2 * qt);
    if (diag) {
#pragma unroll
      for (int mi = 0; mi < 2; ++mi)
#pragma unroll
        for (int nb = 0; nb < 4; ++nb) {
          int col = kt * 64 + nb * 16 + l16;
#pragma unroll
          for (int r = 0; r < 4; ++r) {
            int row = qt * 128 + wave * 32 + mi * 16 + quad * 4 + r;
            p[mi][nb][r] = (col > row) ? 0.f : __expf(s4[mi][nb][r] * scale);
          }
        }
    } else {
#pragma unroll
      for (int mi = 0; mi < 2; ++mi)
#pragma unroll
        for (int nb = 0; nb < 4; ++nb)
#pragma unroll
          for (int r = 0; r < 4; ++r)
            p[mi][nb][r] = __expf(s4[mi][nb][r] * scale);
    }

    bf16x8 pa[2][2];
#pragma unroll
    for (int mi = 0; mi < 2; ++mi) {
#pragma unroll
      for (int nb = 0; nb < 4; ++nb)
#pragma unroll
        for (int r = 0; r < 4; ++r)
          Pl[wave][(quad * 4 + r) * 72 + nb * 16 + l16] = f2bf(p[mi][nb][r]);
      __asm__ __volatile__("s_waitcnt lgkmcnt(0)" ::: "memory");
#pragma unroll
      for (int ks2 = 0; ks2 < 2; ++ks2)
        pa[mi][ks2] = *(const bf16x8*)&Pl[wave][l16 * 72 + ks2 * 32 + quad * 8];
    }

#pragma unroll
    for (int mi = 0; mi < 2; ++mi) {
      float sm = 0.f;
#pragma unroll
      for (int ks2 = 0; ks2 < 2; ++ks2)
#pragma unroll
        for (int j = 0; j < 8; ++j) sm += (float)pa[mi][ks2][j];
      sm += __shfl_xor(sm, 16);
      sm += __shfl_xor(sm, 32);
      lacc[mi] += sm;
    }

    if (kt + 1 < nkt) {
      const u16* kb = kbase + (size_t)(kt + 1) * 64 * QKV_LD;
      const u16* vb2 = vbase + (kt + 1) * 64;
#pragma unroll
      for (int t = 0; t < 4; ++t) {
        int i = wave * 4 + t;
        int row = i * 4 + krow_l;
        int c = kcol_l ^ (row & 15);
        async16(kb + (size_t)row * QKV_LD + c * 8, &Kl[1 - cur][i * 512]);
      }
#pragma unroll
      for (int t = 0; t < 4; ++t) {
        int i = wave * 4 + t;
        int d = i * 8 + vd_l;
        async16(vb2 + (size_t)d * 2048 + vc * 8, &VtL[1 - cur][i * 512]);
      }
    }

#pragma unroll
    for (int mi = 0; mi < 2; ++mi)
#pragma unroll
      for (int db = 0; db < 8; ++db)
#pragma unroll
        for (int ks2 = 0; ks2 < 2; ++ks2)
          o[mi][db] = __builtin_amdgcn_mfma_f32_16x16x32_bf16(pa[mi][ks2], vb[db * 2 + ks2], o[mi][db], 0, 0, 0);
  }

  float* lsh = (float*)&Pl[wave][0];
  if (quad == 0) {
    lsh[l16] = lacc[0];
    lsh[16 + l16] = lacc[1];
  }
  __asm__ __volatile__("s_waitcnt lgkmcnt(0)" ::: "memory");
  __builtin_amdgcn_wave_barrier();
  f32x4 inv[2];
#pragma unroll
  for (int mi = 0; mi < 2; ++mi) {
    f32x4 lv = *(const f32x4*)&lsh[mi * 16 + quad * 4];
#pragma unroll
    for (int r = 0; r < 4; ++r) inv[mi][r] = 1.f / lv[r];
  }
#pragma unroll
  for (int mi = 0; mi < 2; ++mi)
#pragma unroll
    for (int db = 0; db < 8; ++db)
#pragma unroll
      for (int r = 0; r < 4; ++r) {
        int row = qt * 128 + wave * 32 + mi * 16 + quad * 4 + r;
        int col = h * HD + db * 16 + l16;
        attnb[(size_t)row * DIM + col] = f2bf(o[mi][db][r] * inv[mi][r]);
      }
}

extern "C" void kernel_launch(void* const* d_in, const int* in_sizes, int n_in,
                              void* d_out, int out_size, void* d_ws, size_t ws_size,
                              hipStream_t stream) {
  (void)in_sizes; (void)n_in; (void)out_size; (void)ws_size;
  const float* x    = (const float*)d_in[0];
  const float* wq   = (const float*)d_in[1];
  const float* wk   = (const float*)d_in[2];
  const float* wv   = (const float*)d_in[3];
  const float* wo   = (const float*)d_in[4];
  const float* fcos = (const float*)d_in[5];
  const float* fsin = (const float*)d_in[6];
  float* out = (float*)d_out;

  char* ws = (char*)d_ws;
  u16* xb    = (u16*)(ws);                        // 2048x4096 bf16   (16.78 MB)
  u16* wqkvb = (u16*)(ws + (size_t)16777216);     // 6144x4096 bf16   (50.33 MB)
  u16* wob   = (u16*)(ws + (size_t)67108864);     // 4096x4096 bf16   (33.55 MB)
  u16* qkv   = (u16*)(ws + (size_t)100663296);    // 2048x6144 bf16   (25.17 MB)
  u16* attnb = (u16*)(ws + (size_t)125829120);    // 2048x4096 bf16   (16.78 MB)
  u16* vtb   = (u16*)(ws);                        // 8x128x2048 bf16 (4.19 MB) overlays dead xb

  // f32 -> bf16 (fused [wq;wk;wv] so QKV is a single NT GEMM)
  cvt_kernel<<<4096, 256, 0, stream>>>(x, xb, 1048576);
  cvt_kernel<<<8192, 256, 0, stream>>>(wq, wqkvb, 2097152);
  cvt_kernel<<<2048, 256, 0, stream>>>(wk, wqkvb + 16777216, 524288);
  cvt_kernel<<<2048, 256, 0, stream>>>(wv, wqkvb + 20971520, 524288);
  cvt_kernel<<<8192, 256, 0, stream>>>(wo, wob, 2097152);

  // qkv[s, 0:4096]=Q, [4096:5120]=K, [5120:6144]=V
  // 256^2 8-phase GEMM: grid = (2048/256)*(6144/256) = 192 blocks
  gemm_nt8<u16><<<dim3(192), 512, 0, stream>>>(xb, wqkvb, qkv, 6144, 4096, 8);
  // V^T (xb is dead after the QKV GEMM; vtb overlays it)
  vtrans_kernel<<<dim3(32, 2, 8), 256, 0, stream>>>(qkv, vtb);
  rope_kernel<<<20480, 256, 0, stream>>>(qkv, fcos, fsin);
  flash_kernel<<<512, 256, 0, stream>>>(qkv, vtb, attnb);
  // WO: 128x256-tile 8-phase, grid = (2048/128)*(4096/256) = 256 blocks (full fill)
  gemm_nt8w<float><<<dim3(256), 512, 0, stream>>>(attnb, wob, out, 4096, 4096, 16);
}

// Round 4
// 523.357 us; speedup vs baseline: 1.0570x; 1.0156x over previous
//
#include <hip/hip_runtime.h>
#include <hip/hip_bf16.h>

typedef unsigned short u16;
typedef unsigned int u32;
typedef __bf16 bf16x8 __attribute__((ext_vector_type(8)));
typedef float f32x4 __attribute__((ext_vector_type(4)));
typedef u32 u32x4 __attribute__((ext_vector_type(4)));

#define QKV_LD 6144
#define KOFF 4096
#define VOFF 5120
#define HD 128
#define DIM 4096

__device__ __forceinline__ u16 f2bf(float f) {
  union { __hip_bfloat16 h; u16 u; } c;
  c.h = __float2bfloat16(f);
  return c.u;
}
__device__ __forceinline__ float bf2f(u16 u) {
  union { u16 u; __hip_bfloat16 h; } c;
  c.u = u;
  return __bfloat162float(c.h);
}

typedef __attribute__((address_space(1))) const u32 gas_u32;
typedef __attribute__((address_space(3))) u32 las_u32;
__device__ __forceinline__ void async16(const u16* g, u16* l) {
  __builtin_amdgcn_global_load_lds((gas_u32*)g, (las_u32*)l, 16, 0, 0);
}

__device__ __forceinline__ void store_out(u16* p, float v) { *p = f2bf(v); }
__device__ __forceinline__ void store_out(float* p, float v) { *p = v; }

// ---------------- f32 -> bf16 convert, 8 elems/thread ----------------
__global__ __launch_bounds__(256) void cvt_kernel(const float* __restrict__ src,
                                                  u16* __restrict__ dst, int n8) {
  int i = blockIdx.x * 256 + threadIdx.x;
  if (i >= n8) return;
  const f32x4* s4 = (const f32x4*)src;
  f32x4 a = s4[2 * i], b = s4[2 * i + 1];
  u32x4 o;
  o[0] = (u32)f2bf(a[0]) | ((u32)f2bf(a[1]) << 16);
  o[1] = (u32)f2bf(a[2]) | ((u32)f2bf(a[3]) << 16);
  o[2] = (u32)f2bf(b[0]) | ((u32)f2bf(b[1]) << 16);
  o[3] = (u32)f2bf(b[2]) | ((u32)f2bf(b[3]) << 16);
  ((u32x4*)dst)[i] = o;
}

// ======================= 8-phase GEMM machinery =======================
// T1 (XCD swizzle) + T2 (XOR-swizzled LDS via pre-swizzled global src) +
// T3/T4 (8 phases, counted vmcnt, never 0 in main loop) + T5 (setprio).
// Round-3 post-mortem: cycle model shows the DS pipe (reads 4608 + staging
// writes 1024 cyc/iter/CU) exceeds the MFMA wall; and 192 blocks on 256
// CUs wasted 25% of the chip (MfmaUtil 34.4% == per-CU 45% x 0.75 fill).
// Fix: full-fill geometry (round 4) rather than more waitcnt surgery.
#define BAR8 __builtin_amdgcn_s_barrier()
#define VMC(n) asm volatile("s_waitcnt vmcnt(" #n ")" ::: "memory")

// ---------------- NT GEMM: 128x384 tile, 8-phase (QKV: exact 256-block fill)
// Grid 16x16 = 256 blocks = 1/CU. 8 waves (2M x 4N); per-wave output 64x96
// (acc 4x6 = 96 VGPR; B shared by 2 waves, A by 4 -> LDS read traffic
// 160 KB/blk/K-tile vs 192 at 256^2). Slots per buf: {A(128r), B0,B1,B2}.
// Phases per K-tile: (mlo,nlo)->(mlo,nhi)->(mhi,nhi)->(mhi,nlo); frag reads
// {10,6,4,0} b128/phase. One 128-row stage per phase:
//   ph1: buf1.B2<-t1  ph2: buf1.A<-t1  ph3: buf0.B0<-t2  ph4: buf0.B1<-t2
//   ph5: buf0.B2<-t2  ph6: buf0.A<-t2  ph7: buf1.B0<-t3  ph8: buf1.B1<-t3
// Lifetimes (all >=1 barrier-pair after last read): B slots last read ph2/ph6,
// restaged ph3+/ph7+; A last read ph3/ph7, restaged ph6/ph2.
// vmcnt(4) at ph4 (drains ph7,8,1,2 -> buf1 ready for ph5) and at ph8
// (drains ph3-6 -> buf0 ready for next ph1); 2 stages stay in flight.
#define LDAQ(buf, mh, arr)                                                        \
  _Pragma("unroll") for (int mi = 0; mi < 2; ++mi) {                              \
    const int r_ = wm * 64 + (mh) * 32 + mi * 16 + l16;                           \
    const u16* p_ = &lds[buf][0][r_ * 64];                                        \
    _Pragma("unroll") for (int ks = 0; ks < 2; ++ks)                              \
      arr[mi][ks] = *(const bf16x8*)(p_ + (((ks * 4 + quad) ^ (r_ & 7)) << 3));   \
  }

#define LDBQ(buf, nh, arr)                                                        \
  _Pragma("unroll") for (int ni = 0; ni < 3; ++ni) {                              \
    const int gr_ = wn * 96 + (nh) * 48 + ni * 16 + l16;                          \
    const int sl_ = (wn * 96 + (nh) * 48 + ni * 16) >> 7;                         \
    const u16* p_ = &lds[buf][1 + sl_][(gr_ & 127) * 64];                         \
    _Pragma("unroll") for (int ks = 0; ks < 2; ++ks)                              \
      arr[ni][ks] = *(const bf16x8*)(p_ + (((ks * 4 + quad) ^ (gr_ & 7)) << 3));  \
  }

#define MMAQ(mh, nh, af, bf)                                                      \
  __builtin_amdgcn_s_setprio(1);                                                  \
  _Pragma("unroll") for (int mi = 0; mi < 2; ++mi)                                \
  _Pragma("unroll") for (int ni = 0; ni < 3; ++ni)                                \
  _Pragma("unroll") for (int ks = 0; ks < 2; ++ks)                                \
    acc[(mh) * 2 + mi][(nh) * 3 + ni] = __builtin_amdgcn_mfma_f32_16x16x32_bf16(  \
        af[mi][ks], bf[ni][ks], acc[(mh) * 2 + mi][(nh) * 3 + ni], 0, 0, 0);      \
  __builtin_amdgcn_s_setprio(0);

template <typename OutT>
__global__ __launch_bounds__(512, 2) void gemm_nt8q(const u16* __restrict__ A,
                                                    const u16* __restrict__ B,
                                                    OutT* __restrict__ C,
                                                    int N, int K, int MT) {
  __shared__ u16 lds[2][4][128 * 64];  // [buf][A,B0,B1,B2] = 128 KiB
  const int tid = threadIdx.x;
  const int wave = tid >> 6;
  const int lane = tid & 63;
  const int quad = lane >> 4;
  const int l16 = lane & 15;
  const int wm = wave >> 2;  // 0..1 : 64-row band
  const int wn = wave & 3;   // 0..3 : 96-col band

  // bijective XCD-aware swizzle (nwg = 256 -> wg = xcd*32 + off)
  const int nwg = gridDim.x;
  const int bid = blockIdx.x;
  const int qq = nwg >> 3, rr8 = nwg & 7, xcd = bid & 7, off = bid >> 3;
  const int wg = (xcd < rr8 ? xcd * (qq + 1) : rr8 * (qq + 1) + (xcd - rr8) * qq) + off;
  const int bm = wg % MT;
  const int bn = wg / MT;

  const int NIT = K >> 7;  // two 64-wide K-tiles per iteration

  // staging geometry (T2 both-sides rule: pre-swizzled global granule,
  // linear global_load_lds dest -> swizzled LDS, conflict-free ds_read)
  const int srow = (wave << 3) + (lane >> 3);
  const int sgran = (lane & 7) ^ ((lane >> 3) & 7);
  const u16* Abase = A + (size_t)(bm * 128 + srow) * K + sgran * 8;
  const u16* Bbase = B + (size_t)(bn * 384 + srow) * K + sgran * 8;

  auto stageA = [&](int buf, int kt) {
    const u16* g = Abase + (size_t)kt * 64;
    u16* s = &lds[buf][0][0] + wave * (8 * 64);
    async16(g, s);
    async16(g + (size_t)64 * K, s + 64 * 64);
  };
  auto stageB = [&](int buf, int j, int kt) {
    const u16* g = Bbase + (size_t)(j * 128) * K + (size_t)kt * 64;
    u16* s = &lds[buf][1 + j][0] + wave * (8 * 64);
    async16(g, s);
    async16(g + (size_t)64 * K, s + 64 * 64);
  };

  f32x4 acc[4][6];
#pragma unroll
  for (int i = 0; i < 4; ++i)
#pragma unroll
    for (int j = 0; j < 6; ++j) {
      f32x4 z = {0.f, 0.f, 0.f, 0.f};
      acc[i][j] = z;
    }

  // prologue: buf0 <- t0 fully; buf1 <- t1 partially (B0,B1; B2,A come at
  // ph1/ph2 of iter 0). vmcnt(4) drains buf0's 4 stages, leaves buf1's 2.
  stageB(0, 0, 0); stageB(0, 1, 0); stageB(0, 2, 0); stageA(0, 0);
  stageB(1, 0, 1); stageB(1, 1, 1);
  VMC(4);
  BAR8;

  bf16x8 alo[2][2], ahi[2][2], blo[3][2], bhi[3][2];
  for (int it = 0; it < NIT; ++it) {
    const int t1 = 2 * it + 1, t2 = 2 * it + 2, t3 = 2 * it + 3;
    const bool more = (it + 1 < NIT);

    // ---- ph1: (mlo,nlo) on buf0 ----
    LDAQ(0, 0, alo);
    LDBQ(0, 0, blo);
    stageB(1, 2, t1);
    BAR8;
    MMAQ(0, 0, alo, blo);
    BAR8;
    // ---- ph2: (mlo,nhi) ----
    LDBQ(0, 1, bhi);
    stageA(1, t1);
    BAR8;
    MMAQ(0, 1, alo, bhi);
    BAR8;
    // ---- ph3: (mhi,nhi) ----
    LDAQ(0, 1, ahi);
    if (more) stageB(0, 0, t2);
    BAR8;
    MMAQ(1, 1, ahi, bhi);
    BAR8;
    // ---- ph4: (mhi,nlo); buf1 must be resident after this vmcnt ----
    if (more) stageB(0, 1, t2);
    BAR8;
    MMAQ(1, 0, ahi, blo);
    if (more) { VMC(4); } else { VMC(0); }
    BAR8;
    // ---- ph5: (mlo,nlo) on buf1 ----
    LDAQ(1, 0, alo);
    LDBQ(1, 0, blo);
    if (more) stageB(0, 2, t2);
    BAR8;
    MMAQ(0, 0, alo, blo);
    BAR8;
    // ---- ph6: (mlo,nhi) ----
    LDBQ(1, 1, bhi);
    if (more) stageA(0, t2);
    BAR8;
    MMAQ(0, 1, alo, bhi);
    BAR8;
    // ---- ph7: (mhi,nhi) ----
    LDAQ(1, 1, ahi);
    if (more) stageB(1, 0, t3);
    BAR8;
    MMAQ(1, 1, ahi, bhi);
    BAR8;
    // ---- ph8: (mhi,nlo); buf0 must be resident after this vmcnt ----
    if (more) stageB(1, 1, t3);
    BAR8;
    MMAQ(1, 0, ahi, blo);
    if (more) { VMC(4); } else { VMC(0); }
    BAR8;
  }

#pragma unroll
  for (int mh = 0; mh < 2; ++mh)
#pragma unroll
    for (int mi = 0; mi < 2; ++mi) {
      int row = bm * 128 + wm * 64 + mh * 32 + mi * 16 + quad * 4;
#pragma unroll
      for (int nh = 0; nh < 2; ++nh)
#pragma unroll
        for (int ni = 0; ni < 3; ++ni) {
          int col = bn * 384 + wn * 96 + nh * 48 + ni * 16 + l16;
#pragma unroll
          for (int r = 0; r < 4; ++r)
            store_out(&C[(size_t)(row + r) * N + col], acc[mh * 2 + mi][nh * 3 + ni][r]);
        }
    }
}

// ---------------- NT GEMM: 128x256 tile, 8-phase (WO: 256-block fill) -------
#define LDAW(buf, arr)                                                               \
  _Pragma("unroll") for (int qm_ = 0; qm_ < 2; ++qm_)                                \
  _Pragma("unroll") for (int mi = 0; mi < 2; ++mi) {                                 \
    const int r_ = qm_ * 64 + wm * 32 + mi * 16 + l16;                               \
    const u16* p_ = &lds[buf][0][r_ * 64];                                           \
    _Pragma("unroll") for (int ks = 0; ks < 2; ++ks)                                 \
      arr[qm_][mi][ks] = *(const bf16x8*)(p_ + (((ks * 4 + quad) ^ (r_ & 7)) << 3)); \
  }

#define LDBW(buf, h, arr)                                                        \
  _Pragma("unroll") for (int ni = 0; ni < 2; ++ni) {                             \
    const int r_ = wn * 32 + ni * 16 + l16;                                      \
    const u16* p_ = &lds[buf][1 + (h)][r_ * 64];                                 \
    _Pragma("unroll") for (int ks = 0; ks < 2; ++ks)                             \
      arr[ni][ks] = *(const bf16x8*)(p_ + (((ks * 4 + quad) ^ (r_ & 7)) << 3));  \
  }

#define MMAW(qm, qn, af, bf)                                                       \
  __builtin_amdgcn_s_setprio(1);                                                   \
  _Pragma("unroll") for (int mi = 0; mi < 2; ++mi)                                 \
  _Pragma("unroll") for (int ni = 0; ni < 2; ++ni)                                 \
  _Pragma("unroll") for (int ks = 0; ks < 2; ++ks)                                 \
    acc[(qm) * 2 + mi][(qn) * 2 + ni] = __builtin_amdgcn_mfma_f32_16x16x32_bf16(   \
        af[qm][mi][ks], bf[ni][ks], acc[(qm) * 2 + mi][(qn) * 2 + ni], 0, 0, 0);   \
  __builtin_amdgcn_s_setprio(0);

template <typename OutT>
__global__ __launch_bounds__(512, 2) void gemm_nt8w(const u16* __restrict__ A,
                                                    const u16* __restrict__ B,
                                                    OutT* __restrict__ C,
                                                    int N, int K, int MT) {
  __shared__ u16 lds[2][3][128 * 64];  // [buf][A,B0,B1][row*64 + elem] (96 KiB)
  const int tid = threadIdx.x;
  const int wave = tid >> 6;
  const int lane = tid & 63;
  const int quad = lane >> 4;
  const int l16 = lane & 15;
  const int wm = wave >> 2;  // 0..1 : 32-row band within a 64-row half
  const int wn = wave & 3;   // 0..3 : 32-col band within a 128-col half

  const int nwg = gridDim.x;
  const int bid = blockIdx.x;
  const int qq = nwg >> 3, rr8 = nwg & 7, xcd = bid & 7, off = bid >> 3;
  const int wg = (xcd < rr8 ? xcd * (qq + 1) : rr8 * (qq + 1) + (xcd - rr8) * qq) + off;
  const int bm = wg % MT;
  const int bn = wg / MT;

  const int NIT = K >> 7;

  const int srow = (wave << 3) + (lane >> 3);
  const int sgran = (lane & 7) ^ ((lane >> 3) & 7);
  const u16* Abase = A + (size_t)(bm * 128 + srow) * K + sgran * 8;
  const u16* Bbase = B + (size_t)(bn * 256 + srow) * K + sgran * 8;

  auto stageA = [&](int buf, int kt) {
    const u16* g = Abase + (size_t)kt * 64;
    u16* s = &lds[buf][0][0] + wave * (8 * 64);
    async16(g, s);
    async16(g + (size_t)64 * K, s + 64 * 64);
  };
  auto stageB = [&](int buf, int h, int kt) {
    const u16* g = Bbase + (size_t)(h * 128) * K + kt * 64;
    u16* s = &lds[buf][1 + h][0] + wave * (8 * 64);
    async16(g, s);
    async16(g + (size_t)64 * K, s + 64 * 64);
  };

  f32x4 acc[4][4];
#pragma unroll
  for (int i = 0; i < 4; ++i)
#pragma unroll
    for (int j = 0; j < 4; ++j) {
      f32x4 z = {0.f, 0.f, 0.f, 0.f};
      acc[i][j] = z;
    }

  // prologue: tile0 + tile1 fully staged; vmcnt(6) drains tile0 only
  stageA(0, 0); stageB(0, 0, 0); stageB(0, 1, 0);
  stageA(1, 1); stageB(1, 0, 1); stageB(1, 1, 1);
  VMC(6);
  BAR8;

  bf16x8 a[2][2][2], b0f[2][2], b1f[2][2];
  for (int it = 0; it < NIT; ++it) {
    const int t2 = 2 * it + 2, t3 = 2 * it + 3;
    const bool more = (it + 1 < NIT);

    // ---- ph1: q00 on buf0 (all A-frags + B0) ----
    LDAW(0, a);
    LDBW(0, 0, b0f);
    BAR8;
    MMAW(0, 0, a, b0f);
    BAR8;
    // ---- ph2: q01 ----
    LDBW(0, 1, b1f);
    if (more) stageB(0, 0, t2);
    BAR8;
    MMAW(0, 1, a, b1f);
    BAR8;
    // ---- ph3: q11 ----
    if (more) stageA(0, t2);
    BAR8;
    MMAW(1, 1, a, b1f);
    BAR8;
    // ---- ph4: q10; tile boundary vmcnt ----
    if (more) stageB(0, 1, t2);
    BAR8;
    MMAW(1, 0, a, b0f);
    if (more) { VMC(6); } else { VMC(0); }
    BAR8;
    // ---- ph5: q00 on buf1 ----
    LDAW(1, a);
    LDBW(1, 0, b0f);
    BAR8;
    MMAW(0, 0, a, b0f);
    BAR8;
    // ---- ph6: q01 ----
    LDBW(1, 1, b1f);
    if (more) stageB(1, 0, t3);
    BAR8;
    MMAW(0, 1, a, b1f);
    BAR8;
    // ---- ph7: q11 ----
    if (more) stageA(1, t3);
    BAR8;
    MMAW(1, 1, a, b1f);
    BAR8;
    // ---- ph8: q10; tile boundary vmcnt ----
    if (more) stageB(1, 1, t3);
    BAR8;
    MMAW(1, 0, a, b0f);
    if (more) { VMC(6); } else { VMC(0); }
    BAR8;
  }

#pragma unroll
  for (int qm = 0; qm < 2; ++qm)
#pragma unroll
    for (int mi = 0; mi < 2; ++mi) {
      int row = bm * 128 + qm * 64 + wm * 32 + mi * 16 + quad * 4;
#pragma unroll
      for (int qn = 0; qn < 2; ++qn)
#pragma unroll
        for (int ni = 0; ni < 2; ++ni) {
          int col = bn * 256 + qn * 128 + wn * 32 + ni * 16 + l16;
#pragma unroll
          for (int r = 0; r < 4; ++r)
            store_out(&C[(size_t)(row + r) * N + col], acc[qm * 2 + mi][qn * 2 + ni][r]);
        }
    }
}

// ---------------- RoPE in-place on q,k regions of qkv (bf16) ----------------
__global__ __launch_bounds__(256) void rope_kernel(u16* qkv, const float* __restrict__ fcos,
                                                   const float* __restrict__ fsin) {
  int idx = blockIdx.x * 256 + threadIdx.x;
  int row, colbase, fi;
  if (idx < 2048 * 2048) {
    row = idx >> 11;
    int pi = idx & 2047;
    fi = pi & 63;
    colbase = (pi >> 6) * 128 + fi * 2;
  } else {
    int j = idx - 2048 * 2048;
    row = j >> 9;
    int pj = j & 511;
    fi = pj & 63;
    colbase = KOFF + (pj >> 6) * 128 + fi * 2;
  }
  float c = fcos[row * 64 + fi], s = fsin[row * 64 + fi];
  u32* p = (u32*)(qkv + (size_t)row * QKV_LD + colbase);
  u32 v = *p;
  float a = bf2f((u16)(v & 0xffffu));
  float b = bf2f((u16)(v >> 16));
  float xr = a * c - b * s;
  float xi = a * s + b * c;
  *p = (u32)f2bf(xr) | ((u32)f2bf(xi) << 16);
}

// ---------------- V transpose: qkv V region [s][kvh*128+d] -> vt[kvh][d][s] --
__global__ __launch_bounds__(256) void vtrans_kernel(const u16* __restrict__ qkv,
                                                     u16* __restrict__ vt) {
  __shared__ u16 Ls[64 * 72];
  const int tid = threadIdx.x;
  const int st = blockIdx.x, dt = blockIdx.y, kvh = blockIdx.z;
#pragma unroll
  for (int t = 0; t < 2; ++t) {
    int g = t * 256 + tid;
    int s = g >> 3, c = g & 7;
    u32x4 v = *(const u32x4*)(qkv + (size_t)(st * 64 + s) * QKV_LD + VOFF + kvh * HD + dt * 64 + c * 8);
    *(u32x4*)&Ls[s * 72 + c * 8] = v;
  }
  __syncthreads();
#pragma unroll
  for (int t = 0; t < 2; ++t) {
    int g = t * 256 + tid;
    int d = g >> 3, c2 = g & 7;
    u32x4 o;
#pragma unroll
    for (int j = 0; j < 4; ++j) {
      u16 lo = Ls[(c2 * 8 + 2 * j) * 72 + d];
      u16 hi = Ls[(c2 * 8 + 2 * j + 1) * 72 + d];
      o[j] = (u32)lo | ((u32)hi << 16);
    }
    *(u32x4*)(vt + (size_t)(kvh * HD + dt * 64 + d) * 2048 + st * 64 + c2 * 8) = o;
  }
}

// ---------------- Flash attention, causal, GQA 4:1 ----------------
__global__ __launch_bounds__(256, 2) void flash_kernel(const u16* __restrict__ qkv,
                                                       const u16* __restrict__ vt,
                                                       u16* __restrict__ attnb) {
  __shared__ u16 Kl[2][64 * 128];   // [key][d], 16B granules XOR-swizzled by key&15
  __shared__ u16 VtL[2][128 * 64];  // [d][key], 16B granules XOR-swizzled by d&7
  __shared__ u16 Pl[4][16 * 72];    // per-wave P round-trip (reused for both m-blocks)
  const int tid = threadIdx.x;
  const int wave = tid >> 6;
  const int lane = tid & 63;
  const int quad = lane >> 4;
  const int l16 = lane & 15;
  const int lid = blockIdx.x;
  const int h = lid & 31;
  const int z = lid >> 5;              // 0..15
  const int qt = (z < 8) ? z : 23 - z; // pairs (lid, lid+256) sum to 34 iters
  const int kvh = h >> 2;
  const float scale = 0.08838834764831845f; // 1/sqrt(128)
  const int nkt = 2 * qt + 2;

  const int krow_l = (lane >> 4);
  const int kcol_l = (lane & 15);
  const int vd_l = (lane >> 3);
  const int vc = (lane & 7) ^ ((lane >> 3) & 7);

  const u16* kbase = qkv + (size_t)KOFF + kvh * HD;
  const u16* vbase = vt + (size_t)kvh * HD * 2048;

  bf16x8 qf[2][4];
#pragma unroll
  for (int mi = 0; mi < 2; ++mi) {
    const u16* qp = qkv + (size_t)(qt * 128 + wave * 32 + mi * 16 + l16) * QKV_LD + h * HD + quad * 8;
#pragma unroll
    for (int ks = 0; ks < 4; ++ks) qf[mi][ks] = *(const bf16x8*)(qp + ks * 32);
  }

  f32x4 o[2][8];
#pragma unroll
  for (int mi = 0; mi < 2; ++mi)
#pragma unroll
    for (int i = 0; i < 8; ++i) { f32x4 zz = {0.f, 0.f, 0.f, 0.f}; o[mi][i] = zz; }
  float lacc[2] = {0.f, 0.f};

#pragma unroll
  for (int t = 0; t < 4; ++t) {
    int i = wave * 4 + t;
    int row = i * 4 + krow_l;
    int c = kcol_l ^ (row & 15);
    async16(kbase + (size_t)row * QKV_LD + c * 8, &Kl[0][i * 512]);
  }
#pragma unroll
  for (int t = 0; t < 4; ++t) {
    int i = wave * 4 + t;
    int d = i * 8 + vd_l;
    async16(vbase + (size_t)d * 2048 + vc * 8, &VtL[0][i * 512]);
  }

  for (int kt = 0; kt < nkt; ++kt) {
    const int cur = kt & 1;
    __syncthreads();

    f32x4 s4[2][4];
#pragma unroll
    for (int mi = 0; mi < 2; ++mi)
#pragma unroll
      for (int nb = 0; nb < 4; ++nb) { f32x4 zz = {0.f, 0.f, 0.f, 0.f}; s4[mi][nb] = zz; }
#pragma unroll
    for (int nb = 0; nb < 4; ++nb) {
#pragma unroll
      for (int ks = 0; ks < 4; ++ks) {
        int rr = nb * 16 + l16;
        int cc = ((ks * 4 + quad) ^ l16) * 8;
        bf16x8 kf = *(const bf16x8*)&Kl[cur][rr * 128 + cc];
        s4[0][nb] = __builtin_amdgcn_mfma_f32_16x16x32_bf16(qf[0][ks], kf, s4[0][nb], 0, 0, 0);
        s4[1][nb] = __builtin_amdgcn_mfma_f32_16x16x32_bf16(qf[1][ks], kf, s4[1][nb], 0, 0, 0);
      }
    }

    bf16x8 vb[16];
#pragma unroll
    for (int db = 0; db < 8; ++db) {
      int dd = db * 16 + l16;
#pragma unroll
      for (int ks2 = 0; ks2 < 2; ++ks2) {
        int c = (ks2 * 4 + quad) ^ (dd & 7);
        vb[db * 2 + ks2] = *(const bf16x8*)&VtL[cur][dd * 64 + c * 8];
      }
    }

    float p[2][4][4];
    const bool diag = (kt >= 2 * qt);
    if (diag) {
#pragma unroll
      for (int mi = 0; mi < 2; ++mi)
#pragma unroll
        for (int nb = 0; nb < 4; ++nb) {
          int col = kt * 64 + nb * 16 + l16;
#pragma unroll
          for (int r = 0; r < 4; ++r) {
            int row = qt * 128 + wave * 32 + mi * 16 + quad * 4 + r;
            p[mi][nb][r] = (col > row) ? 0.f : __expf(s4[mi][nb][r] * scale);
          }
        }
    } else {
#pragma unroll
      for (int mi = 0; mi < 2; ++mi)
#pragma unroll
        for (int nb = 0; nb < 4; ++nb)
#pragma unroll
          for (int r = 0; r < 4; ++r)
            p[mi][nb][r] = __expf(s4[mi][nb][r] * scale);
    }

    bf16x8 pa[2][2];
#pragma unroll
    for (int mi = 0; mi < 2; ++mi) {
#pragma unroll
      for (int nb = 0; nb < 4; ++nb)
#pragma unroll
        for (int r = 0; r < 4; ++r)
          Pl[wave][(quad * 4 + r) * 72 + nb * 16 + l16] = f2bf(p[mi][nb][r]);
      __asm__ __volatile__("s_waitcnt lgkmcnt(0)" ::: "memory");
#pragma unroll
      for (int ks2 = 0; ks2 < 2; ++ks2)
        pa[mi][ks2] = *(const bf16x8*)&Pl[wave][l16 * 72 + ks2 * 32 + quad * 8];
    }

#pragma unroll
    for (int mi = 0; mi < 2; ++mi) {
      float sm = 0.f;
#pragma unroll
      for (int ks2 = 0; ks2 < 2; ++ks2)
#pragma unroll
        for (int j = 0; j < 8; ++j) sm += (float)pa[mi][ks2][j];
      sm += __shfl_xor(sm, 16);
      sm += __shfl_xor(sm, 32);
      lacc[mi] += sm;
    }

    if (kt + 1 < nkt) {
      const u16* kb = kbase + (size_t)(kt + 1) * 64 * QKV_LD;
      const u16* vb2 = vbase + (kt + 1) * 64;
#pragma unroll
      for (int t = 0; t < 4; ++t) {
        int i = wave * 4 + t;
        int row = i * 4 + krow_l;
        int c = kcol_l ^ (row & 15);
        async16(kb + (size_t)row * QKV_LD + c * 8, &Kl[1 - cur][i * 512]);
      }
#pragma unroll
      for (int t = 0; t < 4; ++t) {
        int i = wave * 4 + t;
        int d = i * 8 + vd_l;
        async16(vb2 + (size_t)d * 2048 + vc * 8, &VtL[1 - cur][i * 512]);
      }
    }

#pragma unroll
    for (int mi = 0; mi < 2; ++mi)
#pragma unroll
      for (int db = 0; db < 8; ++db)
#pragma unroll
        for (int ks2 = 0; ks2 < 2; ++ks2)
          o[mi][db] = __builtin_amdgcn_mfma_f32_16x16x32_bf16(pa[mi][ks2], vb[db * 2 + ks2], o[mi][db], 0, 0, 0);
  }

  float* lsh = (float*)&Pl[wave][0];
  if (quad == 0) {
    lsh[l16] = lacc[0];
    lsh[16 + l16] = lacc[1];
  }
  __asm__ __volatile__("s_waitcnt lgkmcnt(0)" ::: "memory");
  __builtin_amdgcn_wave_barrier();
  f32x4 inv[2];
#pragma unroll
  for (int mi = 0; mi < 2; ++mi) {
    f32x4 lv = *(const f32x4*)&lsh[mi * 16 + quad * 4];
#pragma unroll
    for (int r = 0; r < 4; ++r) inv[mi][r] = 1.f / lv[r];
  }
#pragma unroll
  for (int mi = 0; mi < 2; ++mi)
#pragma unroll
    for (int db = 0; db < 8; ++db)
#pragma unroll
      for (int r = 0; r < 4; ++r) {
        int row = qt * 128 + wave * 32 + mi * 16 + quad * 4 + r;
        int col = h * HD + db * 16 + l16;
        attnb[(size_t)row * DIM + col] = f2bf(o[mi][db][r] * inv[mi][r]);
      }
}

extern "C" void kernel_launch(void* const* d_in, const int* in_sizes, int n_in,
                              void* d_out, int out_size, void* d_ws, size_t ws_size,
                              hipStream_t stream) {
  (void)in_sizes; (void)n_in; (void)out_size; (void)ws_size;
  const float* x    = (const float*)d_in[0];
  const float* wq   = (const float*)d_in[1];
  const float* wk   = (const float*)d_in[2];
  const float* wv   = (const float*)d_in[3];
  const float* wo   = (const float*)d_in[4];
  const float* fcos = (const float*)d_in[5];
  const float* fsin = (const float*)d_in[6];
  float* out = (float*)d_out;

  char* ws = (char*)d_ws;
  u16* xb    = (u16*)(ws);                        // 2048x4096 bf16   (16.78 MB)
  u16* wqkvb = (u16*)(ws + (size_t)16777216);     // 6144x4096 bf16   (50.33 MB)
  u16* wob   = (u16*)(ws + (size_t)67108864);     // 4096x4096 bf16   (33.55 MB)
  u16* qkv   = (u16*)(ws + (size_t)100663296);    // 2048x6144 bf16   (25.17 MB)
  u16* attnb = (u16*)(ws + (size_t)125829120);    // 2048x4096 bf16   (16.78 MB)
  u16* vtb   = (u16*)(ws);                        // 8x128x2048 bf16 (4.19 MB) overlays dead xb

  // f32 -> bf16 (fused [wq;wk;wv] so QKV is a single NT GEMM)
  cvt_kernel<<<4096, 256, 0, stream>>>(x, xb, 1048576);
  cvt_kernel<<<8192, 256, 0, stream>>>(wq, wqkvb, 2097152);
  cvt_kernel<<<2048, 256, 0, stream>>>(wk, wqkvb + 16777216, 524288);
  cvt_kernel<<<2048, 256, 0, stream>>>(wv, wqkvb + 20971520, 524288);
  cvt_kernel<<<8192, 256, 0, stream>>>(wo, wob, 2097152);

  // qkv[s, 0:4096]=Q, [4096:5120]=K, [5120:6144]=V
  // QKV: 128x384-tile 8-phase, grid = (2048/128)*(6144/384) = 256 blocks (full fill)
  gemm_nt8q<u16><<<dim3(256), 512, 0, stream>>>(xb, wqkvb, qkv, 6144, 4096, 16);
  // V^T (xb is dead after the QKV GEMM; vtb overlays it)
  vtrans_kernel<<<dim3(32, 2, 8), 256, 0, stream>>>(qkv, vtb);
  rope_kernel<<<20480, 256, 0, stream>>>(qkv, fcos, fsin);
  flash_kernel<<<512, 256, 0, stream>>>(qkv, vtb, attnb);
  // WO: 128x256-tile 8-phase, grid = (2048/128)*(4096/256) = 256 blocks (full fill)
  gemm_nt8w<float><<<dim3(256), 512, 0, stream>>>(attnb, wob, out, 4096, 4096, 16);
}

// Round 5
// 507.275 us; speedup vs baseline: 1.0905x; 1.0317x over previous
//
#include <hip/hip_runtime.h>
#include <hip/hip_bf16.h>

typedef unsigned short u16;
typedef unsigned int u32;
typedef __bf16 bf16x8 __attribute__((ext_vector_type(8)));
typedef float f32x4 __attribute__((ext_vector_type(4)));
typedef u32 u32x4 __attribute__((ext_vector_type(4)));

#define QKV_LD 6144
#define KOFF 4096
#define VOFF 5120
#define HD 128
#define DIM 4096

__device__ __forceinline__ u16 f2bf(float f) {
  union { __hip_bfloat16 h; u16 u; } c;
  c.h = __float2bfloat16(f);
  return c.u;
}
__device__ __forceinline__ float bf2f(u16 u) {
  union { u16 u; __hip_bfloat16 h; } c;
  c.u = u;
  return __bfloat162float(c.h);
}

typedef __attribute__((address_space(1))) const u32 gas_u32;
typedef __attribute__((address_space(3))) u32 las_u32;
__device__ __forceinline__ void async16(const u16* g, u16* l) {
  __builtin_amdgcn_global_load_lds((gas_u32*)g, (las_u32*)l, 16, 0, 0);
}

__device__ __forceinline__ void store_out(u16* p, float v) { *p = f2bf(v); }
__device__ __forceinline__ void store_out(float* p, float v) { *p = v; }

// ---------------- fused f32 -> bf16 convert for all 5 tensors ----------------
// Region boundaries are multiples of 256 blocks -> branches are block-uniform.
// Units of 8 elems: x 1048576 | wq 2097152 | wk 524288 | wv 524288 | wo 2097152
__global__ __launch_bounds__(256) void cvt_all(const float* __restrict__ x,
                                               const float* __restrict__ wq,
                                               const float* __restrict__ wk,
                                               const float* __restrict__ wv,
                                               const float* __restrict__ wo,
                                               u16* __restrict__ xb,
                                               u16* __restrict__ wqkvb,
                                               u16* __restrict__ wob) {
  int i = blockIdx.x * 256 + threadIdx.x;
  const float* src;
  u16* dst;
  int off;
  if (i < 1048576) {
    src = x; dst = xb; off = i;
  } else if (i < 3145728) {
    src = wq; dst = wqkvb; off = i - 1048576;
  } else if (i < 3670016) {
    src = wk; dst = wqkvb + 16777216; off = i - 3145728;
  } else if (i < 4194304) {
    src = wv; dst = wqkvb + 20971520; off = i - 3670016;
  } else {
    src = wo; dst = wob; off = i - 4194304;
  }
  const f32x4* s4 = (const f32x4*)src;
  f32x4 a = s4[2 * off], b = s4[2 * off + 1];
  u32x4 o;
  o[0] = (u32)f2bf(a[0]) | ((u32)f2bf(a[1]) << 16);
  o[1] = (u32)f2bf(a[2]) | ((u32)f2bf(a[3]) << 16);
  o[2] = (u32)f2bf(b[0]) | ((u32)f2bf(b[1]) << 16);
  o[3] = (u32)f2bf(b[2]) | ((u32)f2bf(b[3]) << 16);
  ((u32x4*)dst)[off] = o;
}

// ======================= 8-phase GEMM machinery =======================
// T1 (XCD swizzle) + T2 (XOR-swizzled LDS via pre-swizzled global src) +
// T3/T4 (8 phases, counted vmcnt, never 0 in main loop) + T5 (setprio).
// Round-4 post-mortem: full-fill geometry worked (109 us, MfmaUtil 41.5%,
// matching the fill-corrected model). Remaining session bottleneck is
// inter-dispatch overhead (~135 us not attributable to any kernel) ->
// round 5 fuses kernels (10 -> 5 dispatches) and folds RoPE into the
// QKV epilogue (kills a 42 MB read-modify-write pass).
#define BAR8 __builtin_amdgcn_s_barrier()
#define VMC(n) asm volatile("s_waitcnt vmcnt(" #n ")" ::: "memory")

// ---------------- NT GEMM: 128x384 tile, 8-phase (QKV: exact 256-block fill)
// Grid 16x16 = 256 blocks = 1/CU. 8 waves (2M x 4N); per-wave output 64x96.
// Slots per buf: {A(128r), B0,B1,B2}. Phases per K-tile:
// (mlo,nlo)->(mlo,nhi)->(mhi,nhi)->(mhi,nlo). One 128-row stage per phase:
//   ph1: buf1.B2<-t1  ph2: buf1.A<-t1  ph3: buf0.B0<-t2  ph4: buf0.B1<-t2
//   ph5: buf0.B2<-t2  ph6: buf0.A<-t2  ph7: buf1.B0<-t3  ph8: buf1.B1<-t3
// vmcnt(4) at ph4/ph8; 2 stages stay in flight.
// ROPE: epilogue applies rotary to cols < 5120 (Q,K) in-register; the
// (col^1) partner lives in lane l16^1 -> __shfl_xor(v,1). V unchanged.
#define LDAQ(buf, mh, arr)                                                        \
  _Pragma("unroll") for (int mi = 0; mi < 2; ++mi) {                              \
    const int r_ = wm * 64 + (mh) * 32 + mi * 16 + l16;                           \
    const u16* p_ = &lds[buf][0][r_ * 64];                                        \
    _Pragma("unroll") for (int ks = 0; ks < 2; ++ks)                              \
      arr[mi][ks] = *(const bf16x8*)(p_ + (((ks * 4 + quad) ^ (r_ & 7)) << 3));   \
  }

#define LDBQ(buf, nh, arr)                                                        \
  _Pragma("unroll") for (int ni = 0; ni < 3; ++ni) {                              \
    const int gr_ = wn * 96 + (nh) * 48 + ni * 16 + l16;                          \
    const int sl_ = (wn * 96 + (nh) * 48 + ni * 16) >> 7;                         \
    const u16* p_ = &lds[buf][1 + sl_][(gr_ & 127) * 64];                         \
    _Pragma("unroll") for (int ks = 0; ks < 2; ++ks)                              \
      arr[ni][ks] = *(const bf16x8*)(p_ + (((ks * 4 + quad) ^ (gr_ & 7)) << 3));  \
  }

#define MMAQ(mh, nh, af, bf)                                                      \
  __builtin_amdgcn_s_setprio(1);                                                  \
  _Pragma("unroll") for (int mi = 0; mi < 2; ++mi)                                \
  _Pragma("unroll") for (int ni = 0; ni < 3; ++ni)                                \
  _Pragma("unroll") for (int ks = 0; ks < 2; ++ks)                                \
    acc[(mh) * 2 + mi][(nh) * 3 + ni] = __builtin_amdgcn_mfma_f32_16x16x32_bf16(  \
        af[mi][ks], bf[ni][ks], acc[(mh) * 2 + mi][(nh) * 3 + ni], 0, 0, 0);      \
  __builtin_amdgcn_s_setprio(0);

template <typename OutT, bool ROPE>
__global__ __launch_bounds__(512, 2) void gemm_nt8q(const u16* __restrict__ A,
                                                    const u16* __restrict__ B,
                                                    OutT* __restrict__ C,
                                                    const float* __restrict__ fcos,
                                                    const float* __restrict__ fsin,
                                                    int N, int K, int MT) {
  __shared__ u16 lds[2][4][128 * 64];  // [buf][A,B0,B1,B2] = 128 KiB
  const int tid = threadIdx.x;
  const int wave = tid >> 6;
  const int lane = tid & 63;
  const int quad = lane >> 4;
  const int l16 = lane & 15;
  const int wm = wave >> 2;  // 0..1 : 64-row band
  const int wn = wave & 3;   // 0..3 : 96-col band

  // bijective XCD-aware swizzle
  const int nwg = gridDim.x;
  const int bid = blockIdx.x;
  const int qq = nwg >> 3, rr8 = nwg & 7, xcd = bid & 7, off = bid >> 3;
  const int wg = (xcd < rr8 ? xcd * (qq + 1) : rr8 * (qq + 1) + (xcd - rr8) * qq) + off;
  const int bm = wg % MT;
  const int bn = wg / MT;

  const int NIT = K >> 7;  // two 64-wide K-tiles per iteration

  // staging geometry (T2 both-sides rule)
  const int srow = (wave << 3) + (lane >> 3);
  const int sgran = (lane & 7) ^ ((lane >> 3) & 7);
  const u16* Abase = A + (size_t)(bm * 128 + srow) * K + sgran * 8;
  const u16* Bbase = B + (size_t)(bn * 384 + srow) * K + sgran * 8;

  auto stageA = [&](int buf, int kt) {
    const u16* g = Abase + (size_t)kt * 64;
    u16* s = &lds[buf][0][0] + wave * (8 * 64);
    async16(g, s);
    async16(g + (size_t)64 * K, s + 64 * 64);
  };
  auto stageB = [&](int buf, int j, int kt) {
    const u16* g = Bbase + (size_t)(j * 128) * K + (size_t)kt * 64;
    u16* s = &lds[buf][1 + j][0] + wave * (8 * 64);
    async16(g, s);
    async16(g + (size_t)64 * K, s + 64 * 64);
  };

  f32x4 acc[4][6];
#pragma unroll
  for (int i = 0; i < 4; ++i)
#pragma unroll
    for (int j = 0; j < 6; ++j) {
      f32x4 z = {0.f, 0.f, 0.f, 0.f};
      acc[i][j] = z;
    }

  // prologue: buf0 <- t0 fully; buf1 <- t1 partially (B0,B1)
  stageB(0, 0, 0); stageB(0, 1, 0); stageB(0, 2, 0); stageA(0, 0);
  stageB(1, 0, 1); stageB(1, 1, 1);
  VMC(4);
  BAR8;

  bf16x8 alo[2][2], ahi[2][2], blo[3][2], bhi[3][2];
  for (int it = 0; it < NIT; ++it) {
    const int t1 = 2 * it + 1, t2 = 2 * it + 2, t3 = 2 * it + 3;
    const bool more = (it + 1 < NIT);

    // ---- ph1: (mlo,nlo) on buf0 ----
    LDAQ(0, 0, alo);
    LDBQ(0, 0, blo);
    stageB(1, 2, t1);
    BAR8;
    MMAQ(0, 0, alo, blo);
    BAR8;
    // ---- ph2: (mlo,nhi) ----
    LDBQ(0, 1, bhi);
    stageA(1, t1);
    BAR8;
    MMAQ(0, 1, alo, bhi);
    BAR8;
    // ---- ph3: (mhi,nhi) ----
    LDAQ(0, 1, ahi);
    if (more) stageB(0, 0, t2);
    BAR8;
    MMAQ(1, 1, ahi, bhi);
    BAR8;
    // ---- ph4: (mhi,nlo); buf1 must be resident after this vmcnt ----
    if (more) stageB(0, 1, t2);
    BAR8;
    MMAQ(1, 0, ahi, blo);
    if (more) { VMC(4); } else { VMC(0); }
    BAR8;
    // ---- ph5: (mlo,nlo) on buf1 ----
    LDAQ(1, 0, alo);
    LDBQ(1, 0, blo);
    if (more) stageB(0, 2, t2);
    BAR8;
    MMAQ(0, 0, alo, blo);
    BAR8;
    // ---- ph6: (mlo,nhi) ----
    LDBQ(1, 1, bhi);
    if (more) stageA(0, t2);
    BAR8;
    MMAQ(0, 1, alo, bhi);
    BAR8;
    // ---- ph7: (mhi,nhi) ----
    LDAQ(1, 1, ahi);
    if (more) stageB(1, 0, t3);
    BAR8;
    MMAQ(1, 1, ahi, bhi);
    BAR8;
    // ---- ph8: (mhi,nlo); buf0 must be resident after this vmcnt ----
    if (more) stageB(1, 1, t3);
    BAR8;
    MMAQ(1, 0, ahi, blo);
    if (more) { VMC(4); } else { VMC(0); }
    BAR8;
  }

#pragma unroll
  for (int mh = 0; mh < 2; ++mh)
#pragma unroll
    for (int mi = 0; mi < 2; ++mi) {
      int row0 = bm * 128 + wm * 64 + mh * 32 + mi * 16 + quad * 4;
#pragma unroll
      for (int nh = 0; nh < 2; ++nh)
#pragma unroll
        for (int ni = 0; ni < 3; ++ni) {
          int col = bn * 384 + wn * 96 + nh * 48 + ni * 16 + l16;
          f32x4 v = acc[mh * 2 + mi][nh * 3 + ni];
          if constexpr (ROPE) {
            // rotary for Q,K cols; pair partner in lane l16^1 (wave-uniform branch:
            // col<5120 is independent of l16 since 5120 % 16 == 0)
            if (col < 5120) {
              const int fi = (col & 127) >> 1;
              const bool odd = col & 1;
#pragma unroll
              for (int r = 0; r < 4; ++r) {
                float pv = __shfl_xor(v[r], 1);
                float c = fcos[(row0 + r) * 64 + fi];
                float sn = fsin[(row0 + r) * 64 + fi];
                v[r] = odd ? (pv * sn + v[r] * c) : (v[r] * c - pv * sn);
              }
            }
          }
#pragma unroll
          for (int r = 0; r < 4; ++r)
            store_out(&C[(size_t)(row0 + r) * N + col], v[r]);
        }
    }
}

// ---------------- NT GEMM: 128x256 tile, 8-phase (WO: 256-block fill) -------
#define LDAW(buf, arr)                                                               \
  _Pragma("unroll") for (int qm_ = 0; qm_ < 2; ++qm_)                                \
  _Pragma("unroll") for (int mi = 0; mi < 2; ++mi) {                                 \
    const int r_ = qm_ * 64 + wm * 32 + mi * 16 + l16;                               \
    const u16* p_ = &lds[buf][0][r_ * 64];                                           \
    _Pragma("unroll") for (int ks = 0; ks < 2; ++ks)                                 \
      arr[qm_][mi][ks] = *(const bf16x8*)(p_ + (((ks * 4 + quad) ^ (r_ & 7)) << 3)); \
  }

#define LDBW(buf, h, arr)                                                        \
  _Pragma("unroll") for (int ni = 0; ni < 2; ++ni) {                             \
    const int r_ = wn * 32 + ni * 16 + l16;                                      \
    const u16* p_ = &lds[buf][1 + (h)][r_ * 64];                                 \
    _Pragma("unroll") for (int ks = 0; ks < 2; ++ks)                             \
      arr[ni][ks] = *(const bf16x8*)(p_ + (((ks * 4 + quad) ^ (r_ & 7)) << 3));  \
  }

#define MMAW(qm, qn, af, bf)                                                       \
  __builtin_amdgcn_s_setprio(1);                                                   \
  _Pragma("unroll") for (int mi = 0; mi < 2; ++mi)                                 \
  _Pragma("unroll") for (int ni = 0; ni < 2; ++ni)                                 \
  _Pragma("unroll") for (int ks = 0; ks < 2; ++ks)                                 \
    acc[(qm) * 2 + mi][(qn) * 2 + ni] = __builtin_amdgcn_mfma_f32_16x16x32_bf16(   \
        af[qm][mi][ks], bf[ni][ks], acc[(qm) * 2 + mi][(qn) * 2 + ni], 0, 0, 0);   \
  __builtin_amdgcn_s_setprio(0);

template <typename OutT>
__global__ __launch_bounds__(512, 2) void gemm_nt8w(const u16* __restrict__ A,
                                                    const u16* __restrict__ B,
                                                    OutT* __restrict__ C,
                                                    int N, int K, int MT) {
  __shared__ u16 lds[2][3][128 * 64];  // [buf][A,B0,B1][row*64 + elem] (96 KiB)
  const int tid = threadIdx.x;
  const int wave = tid >> 6;
  const int lane = tid & 63;
  const int quad = lane >> 4;
  const int l16 = lane & 15;
  const int wm = wave >> 2;  // 0..1 : 32-row band within a 64-row half
  const int wn = wave & 3;   // 0..3 : 32-col band within a 128-col half

  const int nwg = gridDim.x;
  const int bid = blockIdx.x;
  const int qq = nwg >> 3, rr8 = nwg & 7, xcd = bid & 7, off = bid >> 3;
  const int wg = (xcd < rr8 ? xcd * (qq + 1) : rr8 * (qq + 1) + (xcd - rr8) * qq) + off;
  const int bm = wg % MT;
  const int bn = wg / MT;

  const int NIT = K >> 7;

  const int srow = (wave << 3) + (lane >> 3);
  const int sgran = (lane & 7) ^ ((lane >> 3) & 7);
  const u16* Abase = A + (size_t)(bm * 128 + srow) * K + sgran * 8;
  const u16* Bbase = B + (size_t)(bn * 256 + srow) * K + sgran * 8;

  auto stageA = [&](int buf, int kt) {
    const u16* g = Abase + (size_t)kt * 64;
    u16* s = &lds[buf][0][0] + wave * (8 * 64);
    async16(g, s);
    async16(g + (size_t)64 * K, s + 64 * 64);
  };
  auto stageB = [&](int buf, int h, int kt) {
    const u16* g = Bbase + (size_t)(h * 128) * K + kt * 64;
    u16* s = &lds[buf][1 + h][0] + wave * (8 * 64);
    async16(g, s);
    async16(g + (size_t)64 * K, s + 64 * 64);
  };

  f32x4 acc[4][4];
#pragma unroll
  for (int i = 0; i < 4; ++i)
#pragma unroll
    for (int j = 0; j < 4; ++j) {
      f32x4 z = {0.f, 0.f, 0.f, 0.f};
      acc[i][j] = z;
    }

  // prologue: tile0 + tile1 fully staged; vmcnt(6) drains tile0 only
  stageA(0, 0); stageB(0, 0, 0); stageB(0, 1, 0);
  stageA(1, 1); stageB(1, 0, 1); stageB(1, 1, 1);
  VMC(6);
  BAR8;

  bf16x8 a[2][2][2], b0f[2][2], b1f[2][2];
  for (int it = 0; it < NIT; ++it) {
    const int t2 = 2 * it + 2, t3 = 2 * it + 3;
    const bool more = (it + 1 < NIT);

    // ---- ph1: q00 on buf0 (all A-frags + B0) ----
    LDAW(0, a);
    LDBW(0, 0, b0f);
    BAR8;
    MMAW(0, 0, a, b0f);
    BAR8;
    // ---- ph2: q01 ----
    LDBW(0, 1, b1f);
    if (more) stageB(0, 0, t2);
    BAR8;
    MMAW(0, 1, a, b1f);
    BAR8;
    // ---- ph3: q11 ----
    if (more) stageA(0, t2);
    BAR8;
    MMAW(1, 1, a, b1f);
    BAR8;
    // ---- ph4: q10; tile boundary vmcnt ----
    if (more) stageB(0, 1, t2);
    BAR8;
    MMAW(1, 0, a, b0f);
    if (more) { VMC(6); } else { VMC(0); }
    BAR8;
    // ---- ph5: q00 on buf1 ----
    LDAW(1, a);
    LDBW(1, 0, b0f);
    BAR8;
    MMAW(0, 0, a, b0f);
    BAR8;
    // ---- ph6: q01 ----
    LDBW(1, 1, b1f);
    if (more) stageB(1, 0, t3);
    BAR8;
    MMAW(0, 1, a, b1f);
    BAR8;
    // ---- ph7: q11 ----
    if (more) stageA(1, t3);
    BAR8;
    MMAW(1, 1, a, b1f);
    BAR8;
    // ---- ph8: q10; tile boundary vmcnt ----
    if (more) stageB(1, 1, t3);
    BAR8;
    MMAW(1, 0, a, b0f);
    if (more) { VMC(6); } else { VMC(0); }
    BAR8;
  }

#pragma unroll
  for (int qm = 0; qm < 2; ++qm)
#pragma unroll
    for (int mi = 0; mi < 2; ++mi) {
      int row = bm * 128 + qm * 64 + wm * 32 + mi * 16 + quad * 4;
#pragma unroll
      for (int qn = 0; qn < 2; ++qn)
#pragma unroll
        for (int ni = 0; ni < 2; ++ni) {
          int col = bn * 256 + qn * 128 + wn * 32 + ni * 16 + l16;
#pragma unroll
          for (int r = 0; r < 4; ++r)
            store_out(&C[(size_t)(row + r) * N + col], acc[qm * 2 + mi][qn * 2 + ni][r]);
        }
    }
}

// ---------------- V transpose: qkv V region [s][kvh*128+d] -> vt[kvh][d][s] --
__global__ __launch_bounds__(256) void vtrans_kernel(const u16* __restrict__ qkv,
                                                     u16* __restrict__ vt) {
  __shared__ u16 Ls[64 * 72];
  const int tid = threadIdx.x;
  const int st = blockIdx.x, dt = blockIdx.y, kvh = blockIdx.z;
#pragma unroll
  for (int t = 0; t < 2; ++t) {
    int g = t * 256 + tid;
    int s = g >> 3, c = g & 7;
    u32x4 v = *(const u32x4*)(qkv + (size_t)(st * 64 + s) * QKV_LD + VOFF + kvh * HD + dt * 64 + c * 8);
    *(u32x4*)&Ls[s * 72 + c * 8] = v;
  }
  __syncthreads();
#pragma unroll
  for (int t = 0; t < 2; ++t) {
    int g = t * 256 + tid;
    int d = g >> 3, c2 = g & 7;
    u32x4 o;
#pragma unroll
    for (int j = 0; j < 4; ++j) {
      u16 lo = Ls[(c2 * 8 + 2 * j) * 72 + d];
      u16 hi = Ls[(c2 * 8 + 2 * j + 1) * 72 + d];
      o[j] = (u32)lo | ((u32)hi << 16);
    }
    *(u32x4*)(vt + (size_t)(kvh * HD + dt * 64 + d) * 2048 + st * 64 + c2 * 8) = o;
  }
}

// ---------------- Flash attention, causal, GQA 4:1 ----------------
__global__ __launch_bounds__(256, 2) void flash_kernel(const u16* __restrict__ qkv,
                                                       const u16* __restrict__ vt,
                                                       u16* __restrict__ attnb) {
  __shared__ u16 Kl[2][64 * 128];   // [key][d], 16B granules XOR-swizzled by key&15
  __shared__ u16 VtL[2][128 * 64];  // [d][key], 16B granules XOR-swizzled by d&7
  __shared__ u16 Pl[4][16 * 72];    // per-wave P round-trip (reused for both m-blocks)
  const int tid = threadIdx.x;
  const int wave = tid >> 6;
  const int lane = tid & 63;
  const int quad = lane >> 4;
  const int l16 = lane & 15;
  const int lid = blockIdx.x;
  const int h = lid & 31;
  const int z = lid >> 5;              // 0..15
  const int qt = (z < 8) ? z : 23 - z; // pairs (lid, lid+256) sum to 34 iters
  const int kvh = h >> 2;
  const float scale = 0.08838834764831845f; // 1/sqrt(128)
  const int nkt = 2 * qt + 2;

  const int krow_l = (lane >> 4);
  const int kcol_l = (lane & 15);
  const int vd_l = (lane >> 3);
  const int vc = (lane & 7) ^ ((lane >> 3) & 7);

  const u16* kbase = qkv + (size_t)KOFF + kvh * HD;
  const u16* vbase = vt + (size_t)kvh * HD * 2048;

  bf16x8 qf[2][4];
#pragma unroll
  for (int mi = 0; mi < 2; ++mi) {
    const u16* qp = qkv + (size_t)(qt * 128 + wave * 32 + mi * 16 + l16) * QKV_LD + h * HD + quad * 8;
#pragma unroll
    for (int ks = 0; ks < 4; ++ks) qf[mi][ks] = *(const bf16x8*)(qp + ks * 32);
  }

  f32x4 o[2][8];
#pragma unroll
  for (int mi = 0; mi < 2; ++mi)
#pragma unroll
    for (int i = 0; i < 8; ++i) { f32x4 zz = {0.f, 0.f, 0.f, 0.f}; o[mi][i] = zz; }
  float lacc[2] = {0.f, 0.f};

#pragma unroll
  for (int t = 0; t < 4; ++t) {
    int i = wave * 4 + t;
    int row = i * 4 + krow_l;
    int c = kcol_l ^ (row & 15);
    async16(kbase + (size_t)row * QKV_LD + c * 8, &Kl[0][i * 512]);
  }
#pragma unroll
  for (int t = 0; t < 4; ++t) {
    int i = wave * 4 + t;
    int d = i * 8 + vd_l;
    async16(vbase + (size_t)d * 2048 + vc * 8, &VtL[0][i * 512]);
  }

  for (int kt = 0; kt < nkt; ++kt) {
    const int cur = kt & 1;
    __syncthreads();

    f32x4 s4[2][4];
#pragma unroll
    for (int mi = 0; mi < 2; ++mi)
#pragma unroll
      for (int nb = 0; nb < 4; ++nb) { f32x4 zz = {0.f, 0.f, 0.f, 0.f}; s4[mi][nb] = zz; }
#pragma unroll
    for (int nb = 0; nb < 4; ++nb) {
#pragma unroll
      for (int ks = 0; ks < 4; ++ks) {
        int rr = nb * 16 + l16;
        int cc = ((ks * 4 + quad) ^ l16) * 8;
        bf16x8 kf = *(const bf16x8*)&Kl[cur][rr * 128 + cc];
        s4[0][nb] = __builtin_amdgcn_mfma_f32_16x16x32_bf16(qf[0][ks], kf, s4[0][nb], 0, 0, 0);
        s4[1][nb] = __builtin_amdgcn_mfma_f32_16x16x32_bf16(qf[1][ks], kf, s4[1][nb], 0, 0, 0);
      }
    }

    bf16x8 vb[16];
#pragma unroll
    for (int db = 0; db < 8; ++db) {
      int dd = db * 16 + l16;
#pragma unroll
      for (int ks2 = 0; ks2 < 2; ++ks2) {
        int c = (ks2 * 4 + quad) ^ (dd & 7);
        vb[db * 2 + ks2] = *(const bf16x8*)&VtL[cur][dd * 64 + c * 8];
      }
    }

    float p[2][4][4];
    const bool diag = (kt >= 2 * qt);
    if (diag) {
#pragma unroll
      for (int mi = 0; mi < 2; ++mi)
#pragma unroll
        for (int nb = 0; nb < 4; ++nb) {
          int col = kt * 64 + nb * 16 + l16;
#pragma unroll
          for (int r = 0; r < 4; ++r) {
            int row = qt * 128 + wave * 32 + mi * 16 + quad * 4 + r;
            p[mi][nb][r] = (col > row) ? 0.f : __expf(s4[mi][nb][r] * scale);
          }
        }
    } else {
#pragma unroll
      for (int mi = 0; mi < 2; ++mi)
#pragma unroll
        for (int nb = 0; nb < 4; ++nb)
#pragma unroll
          for (int r = 0; r < 4; ++r)
            p[mi][nb][r] = __expf(s4[mi][nb][r] * scale);
    }

    bf16x8 pa[2][2];
#pragma unroll
    for (int mi = 0; mi < 2; ++mi) {
#pragma unroll
      for (int nb = 0; nb < 4; ++nb)
#pragma unroll
        for (int r = 0; r < 4; ++r)
          Pl[wave][(quad * 4 + r) * 72 + nb * 16 + l16] = f2bf(p[mi][nb][r]);
      __asm__ __volatile__("s_waitcnt lgkmcnt(0)" ::: "memory");
#pragma unroll
      for (int ks2 = 0; ks2 < 2; ++ks2)
        pa[mi][ks2] = *(const bf16x8*)&Pl[wave][l16 * 72 + ks2 * 32 + quad * 8];
    }

#pragma unroll
    for (int mi = 0; mi < 2; ++mi) {
      float sm = 0.f;
#pragma unroll
      for (int ks2 = 0; ks2 < 2; ++ks2)
#pragma unroll
        for (int j = 0; j < 8; ++j) sm += (float)pa[mi][ks2][j];
      sm += __shfl_xor(sm, 16);
      sm += __shfl_xor(sm, 32);
      lacc[mi] += sm;
    }

    if (kt + 1 < nkt) {
      const u16* kb = kbase + (size_t)(kt + 1) * 64 * QKV_LD;
      const u16* vb2 = vbase + (kt + 1) * 64;
#pragma unroll
      for (int t = 0; t < 4; ++t) {
        int i = wave * 4 + t;
        int row = i * 4 + krow_l;
        int c = kcol_l ^ (row & 15);
        async16(kb + (size_t)row * QKV_LD + c * 8, &Kl[1 - cur][i * 512]);
      }
#pragma unroll
      for (int t = 0; t < 4; ++t) {
        int i = wave * 4 + t;
        int d = i * 8 + vd_l;
        async16(vb2 + (size_t)d * 2048 + vc * 8, &VtL[1 - cur][i * 512]);
      }
    }

#pragma unroll
    for (int mi = 0; mi < 2; ++mi)
#pragma unroll
      for (int db = 0; db < 8; ++db)
#pragma unroll
        for (int ks2 = 0; ks2 < 2; ++ks2)
          o[mi][db] = __builtin_amdgcn_mfma_f32_16x16x32_bf16(pa[mi][ks2], vb[db * 2 + ks2], o[mi][db], 0, 0, 0);
  }

  float* lsh = (float*)&Pl[wave][0];
  if (quad == 0) {
    lsh[l16] = lacc[0];
    lsh[16 + l16] = lacc[1];
  }
  __asm__ __volatile__("s_waitcnt lgkmcnt(0)" ::: "memory");
  __builtin_amdgcn_wave_barrier();
  f32x4 inv[2];
#pragma unroll
  for (int mi = 0; mi < 2; ++mi) {
    f32x4 lv = *(const f32x4*)&lsh[mi * 16 + quad * 4];
#pragma unroll
    for (int r = 0; r < 4; ++r) inv[mi][r] = 1.f / lv[r];
  }
#pragma unroll
  for (int mi = 0; mi < 2; ++mi)
#pragma unroll
    for (int db = 0; db < 8; ++db)
#pragma unroll
      for (int r = 0; r < 4; ++r) {
        int row = qt * 128 + wave * 32 + mi * 16 + quad * 4 + r;
        int col = h * HD + db * 16 + l16;
        attnb[(size_t)row * DIM + col] = f2bf(o[mi][db][r] * inv[mi][r]);
      }
}

extern "C" void kernel_launch(void* const* d_in, const int* in_sizes, int n_in,
                              void* d_out, int out_size, void* d_ws, size_t ws_size,
                              hipStream_t stream) {
  (void)in_sizes; (void)n_in; (void)out_size; (void)ws_size;
  const float* x    = (const float*)d_in[0];
  const float* wq   = (const float*)d_in[1];
  const float* wk   = (const float*)d_in[2];
  const float* wv   = (const float*)d_in[3];
  const float* wo   = (const float*)d_in[4];
  const float* fcos = (const float*)d_in[5];
  const float* fsin = (const float*)d_in[6];
  float* out = (float*)d_out;

  char* ws = (char*)d_ws;
  u16* xb    = (u16*)(ws);                        // 2048x4096 bf16   (16.78 MB)
  u16* wqkvb = (u16*)(ws + (size_t)16777216);     // 6144x4096 bf16   (50.33 MB)
  u16* wob   = (u16*)(ws + (size_t)67108864);     // 4096x4096 bf16   (33.55 MB)
  u16* qkv   = (u16*)(ws + (size_t)100663296);    // 2048x6144 bf16   (25.17 MB)
  u16* attnb = (u16*)(ws + (size_t)125829120);    // 2048x4096 bf16   (16.78 MB)
  u16* vtb   = (u16*)(ws);                        // 8x128x2048 bf16 (4.19 MB) overlays dead xb

  // fused f32 -> bf16 for all tensors (1 launch instead of 5)
  cvt_all<<<24576, 256, 0, stream>>>(x, wq, wk, wv, wo, xb, wqkvb, wob);

  // qkv[s, 0:4096]=Q, [4096:5120]=K, [5120:6144]=V; RoPE fused in epilogue
  gemm_nt8q<u16, true><<<dim3(256), 512, 0, stream>>>(xb, wqkvb, qkv, fcos, fsin, 6144, 4096, 16);
  // V^T (xb is dead after the QKV GEMM; vtb overlays it)
  vtrans_kernel<<<dim3(32, 2, 8), 256, 0, stream>>>(qkv, vtb);
  flash_kernel<<<512, 256, 0, stream>>>(qkv, vtb, attnb);
  // WO: 128x256-tile 8-phase, grid = (2048/128)*(4096/256) = 256 blocks (full fill)
  gemm_nt8w<float><<<dim3(256), 512, 0, stream>>>(attnb, wob, out, 4096, 4096, 16);
}